// Round 6
// baseline (225.332 us; speedup 1.0000x reference)
//
#include <hip/hip_runtime.h>
#include <math.h>

#define B 4
#define H 224
#define W 224
#define C 64
#define K 8
#define WC (W*C)        // 14336
#define HWC (H*W*C)     // 3211264

__device__ inline float wave_reduce_min(float v) {
  #pragma unroll
  for (int off = 32; off > 0; off >>= 1)
    v = fminf(v, __shfl_down(v, off, 64));
  return v;
}
__device__ inline float wave_reduce_max(float v) {
  #pragma unroll
  for (int off = 32; off > 0; off >>= 1)
    v = fmaxf(v, __shfl_down(v, off, 64));
  return v;
}

struct FalseT { static constexpr bool value = false; };
struct TrueT  { static constexpr bool value = true; };

// ================= FAST PATH =================

// ---- Kernel A: float4 RAW column prefix sums + per-block min/max partials ----
// One block per (b,w), 256 threads = 16 h-segments x 16 channel-groups-of-4.
// Single pass over x (16B/lane): min/max partials ride along on the
// register-resident data, P written RAW (unnormalized) as float4.
// Every sub-combination HW-verified: float4 addressing + min/max + segsum
// exchange = R2 k_vpfx_coop phase 1; raw-P + partials = R1 k_vpfx_raw.
__global__ __launch_bounds__(256) void k_vpfx_raw4(const float* __restrict__ x,
                                                   float* __restrict__ P,
                                                   float* __restrict__ pmin,
                                                   float* __restrict__ pmax) {
  int bid = blockIdx.x;           // b*W + w
  int b = bid / W, w = bid % W;
  int seg = threadIdx.x >> 4;     // [0,16) h-segment of 14 rows
  int chg = threadIdx.x & 15;     // [0,16) channel group of 4
  int wv  = threadIdx.x >> 6;

  const size_t colbase = (size_t)b*HWC + (size_t)w*C;   // multiple of 4
  const float4* xp4 = (const float4*)(x + colbase);
  const int RS4 = WC / 4;         // float4 row stride = 3584
  const int r0 = seg * 14;

  // --- load 14 rows x 4 channels; segment sums + min/max in registers ---
  float4 v4[14];
  #pragma unroll
  for (int j = 0; j < 14; ++j) v4[j] = xp4[(size_t)(r0 + j) * RS4 + chg];

  float4 s4 = v4[0];
  float vmin = fminf(fminf(v4[0].x, v4[0].y), fminf(v4[0].z, v4[0].w));
  float vmax = fmaxf(fmaxf(v4[0].x, v4[0].y), fmaxf(v4[0].z, v4[0].w));
  #pragma unroll
  for (int j = 1; j < 14; ++j) {
    s4.x += v4[j].x; s4.y += v4[j].y; s4.z += v4[j].z; s4.w += v4[j].w;
    vmin = fminf(vmin, fminf(fminf(v4[j].x, v4[j].y), fminf(v4[j].z, v4[j].w)));
    vmax = fmaxf(vmax, fmaxf(fmaxf(v4[j].x, v4[j].y), fmaxf(v4[j].z, v4[j].w)));
  }

  __shared__ float4 segsum[16][16];   // [seg][chg]
  __shared__ float smin[4], smax[4];
  segsum[seg][chg] = s4;
  float wmn = wave_reduce_min(vmin), wmx = wave_reduce_max(vmax);
  if ((threadIdx.x & 63) == 0) { smin[wv] = wmn; smax[wv] = wmx; }
  __syncthreads();

  if (threadIdx.x == 0) {
    pmin[bid] = fminf(fminf(smin[0], smin[1]), fminf(smin[2], smin[3]));
    pmax[bid] = fmaxf(fmaxf(smax[0], smax[1]), fmaxf(smax[2], smax[3]));
  }

  // Offset = sum of earlier segments for this channel group (broadcast reads)
  float4 o4 = {0.f, 0.f, 0.f, 0.f};
  #pragma unroll
  for (int ss = 0; ss < 16; ++ss) {
    if (ss < seg) {
      float4 t = segsum[ss][chg];
      o4.x += t.x; o4.y += t.y; o4.z += t.z; o4.w += t.w;
    }
  }

  // --- RAW prefix write (float4) ---
  float4* Pp4 = (float4*)(P + colbase);
  float ax = o4.x, ay = o4.y, az = o4.z, aw = o4.w;
  #pragma unroll
  for (int j = 0; j < 14; ++j) {
    ax += v4[j].x; ay += v4[j].y; az += v4[j].z; aw += v4[j].w;
    float4 outv; outv.x = ax; outv.y = ay; outv.z = az; outv.w = aw;
    Pp4[(size_t)(r0 + j) * RS4 + chg] = outv;
  }
}

// ---- Kernel B: VERBATIM R1 k_main2 (deferred normalization; R1-verified) ----
__global__ __launch_bounds__(128) void k_main2(
    const float* __restrict__ P, const float* __restrict__ x,
    const float* __restrict__ pmin, const float* __restrict__ pmax,
    const float* __restrict__ ols, const float* __restrict__ anchors,
    const float* __restrict__ hwidths, const float* __restrict__ bn_gamma,
    const float* __restrict__ bn_beta, const float* __restrict__ bn_mean,
    const float* __restrict__ bn_var, float* __restrict__ out) {
  int xcd  = blockIdx.x & 7;
  int i    = blockIdx.x >> 3;        // [0,448)
  int rg   = xcd * 112 + (i >> 2);   // global row in [0,896)
  int wave = threadIdx.x >> 6, c = threadIdx.x & 63;
  int chunk = (i & 3) * 2 + wave;    // [0,8)
  int b = rg / H, h = rg % H;
  int w0 = chunk * 28;

  // --- finalize per-sample min/max from 224 partials (L2-hot) ---
  float vmin = INFINITY, vmax = -INFINITY;
  for (int ii = threadIdx.x; ii < W; ii += 128) {
    vmin = fminf(vmin, pmin[b*W + ii]);
    vmax = fmaxf(vmax, pmax[b*W + ii]);
  }
  vmin = wave_reduce_min(vmin);
  vmax = wave_reduce_max(vmax);
  __shared__ float sred[4];
  if ((threadIdx.x & 63) == 0) { sred[wave*2] = vmin; sred[wave*2+1] = vmax; }
  __syncthreads();
  float xmin = fminf(sred[0], sred[2]);
  float xmax = fmaxf(sred[1], sred[3]);
  float rng  = xmax - xmin + 1e-6f;
  float epsp = 1e-6f * rng;          // eps lifted to the unnormalized domain

  const float LN2 = 0.69314718055994530942f;
  float wg0 = ols[0], wg1 = ols[1], wg2 = ols[2], wg3 = ols[3];
  float l0 = LN2, l1 = 2.f*LN2, l2 = 3.f*LN2, l3 = 4.f*LN2;
  float wsum = wg0 + wg1 + wg2 + wg3;
  float lrbar = (wg0*l0 + wg1*l1 + wg2*l2 + wg3*l3) / wsum;
  float d0 = l0-lrbar, d1 = l1-lrbar, d2 = l2-lrbar, d3 = l3-lrbar;
  float den = wg0*d0*d0 + wg1*d1*d1 + wg2*d2*d2 + wg3*d3*d3;
  float c0 = wg0*d0/den, c1 = wg1*d1/den, c2 = wg2*d2/den, c3 = wg3*d3/den;

  float scl  = bn_gamma[c] * rsqrtf(bn_var[c] + 1e-3f);
  float bofs = bn_beta[c] - bn_mean[c] * scl;
  float anc[K], wd[K];
  #pragma unroll
  for (int k = 0; k < K; ++k) { anc[k] = anchors[c*K + k]; wd[k] = hwidths[c*K + k]; }

  const int hiA[4] = {1, 2, 4, 8};
  const int loA[4] = {0, 1, 3, 7};
  const int rA[4]  = {2, 4, 8, 16};
  const float* pt[4]; const float* pb[4]; float fb[4];
  float Anh[4], Kin[4];
  #pragma unroll
  for (int s = 0; s < 4; ++s) {
    int ht = h + hiA[s]; if (ht > H-1) ht = H-1;
    int hb = h - loA[s] - 1;
    int hbc = hb < 0 ? 0 : hb;
    pt[s] = P + (size_t)b*HWC + (size_t)ht*WC + c;
    pb[s] = P + (size_t)b*HWC + (size_t)hbc*WC + c;
    fb[s] = hb < 0 ? 0.f : 1.f;
    int h0 = h - loA[s]; if (h0 < 0) h0 = 0;
    int nv = ht - h0 + 1;              // in-bounds rows of the vertical window
    Anh[s] = -(float)nv * xmin;        // per-column xmin correction factor
    Kin[s] = (float)rA[s] * Anh[s] + epsp;   // interior: nh == r, eps folded
  }

  const float* xrow = x   + (size_t)b*HWC + (size_t)h*WC + c;
  float*       orow = out + (size_t)b*HWC + (size_t)h*WC + c;

  auto tloop = [&](auto EDGEC) {
    constexpr bool EDGE = decltype(EDGEC)::value;
    float ring2[2]   = {0,0};
    float ring4[4]   = {0,0,0,0};
    float ring8[8]   = {0,0,0,0,0,0,0,0};
    float ring16[16] = {0,0,0,0,0,0,0,0,0,0,0,0,0,0,0,0};
    float T0 = 0.f, T1 = 0.f, T2 = 0.f, T3 = 0.f;
    float abuf[8] = {0,0,0,0,0,0,0,0};

    for (int t0 = 0; t0 < 48; t0 += 16) {
      #pragma unroll
      for (int u = 0; u < 16; ++u) {
        int t  = t0 + u;
        int wr = w0 - 7 + t;
        float m0, m1, m2, m3;
        if constexpr (EDGE) {
          m0 = m1 = m2 = m3 = 0.f;
          if (wr >= 0 && wr < W) {
            int off = wr * C;
            m0 = pt[0][off] - fb[0]*pb[0][off];
            m1 = pt[1][off] - fb[1]*pb[1][off];
            m2 = pt[2][off] - fb[2]*pb[2][off];
            m3 = pt[3][off] - fb[3]*pb[3][off];
          }
        } else {
          int off = wr * C;
          m0 = pt[0][off] - fb[0]*pb[0][off];
          m1 = pt[1][off] - fb[1]*pb[1][off];
          m2 = pt[2][off] - fb[2]*pb[2][off];
          m3 = pt[3][off] - fb[3]*pb[3][off];
        }
        T0 += m0 - ring2[u&1];  ring2[u&1]  = m0;
        T1 += m1 - ring4[u&3];  ring4[u&3]  = m1;
        T2 += m2 - ring8[u&7];  ring8[u&7]  = m2;
        T3 += m3 - ring16[u];   ring16[u]   = m3;

        float a0, a1, a2, a3;
        if constexpr (EDGE) {
          float nh0 = (float)(min(wr, W-1) - max(wr-1,  0) + 1);
          float nh1 = (float)(min(wr, W-1) - max(wr-3,  0) + 1);
          float nh2 = (float)(min(wr, W-1) - max(wr-7,  0) + 1);
          float nh3 = (float)(min(wr, W-1) - max(wr-15, 0) + 1);
          a0 = fmaxf(fmaf(Anh[0], nh0, T0) + epsp, epsp);
          a1 = fmaxf(fmaf(Anh[1], nh1, T1) + epsp, epsp);
          a2 = fmaxf(fmaf(Anh[2], nh2, T2) + epsp, epsp);
          a3 = fmaxf(fmaf(Anh[3], nh3, T3) + epsp, epsp);
        } else {
          a0 = fmaxf(T0 + Kin[0], epsp);
          a1 = fmaxf(T1 + Kin[1], epsp);
          a2 = fmaxf(T2 + Kin[2], epsp);
          a3 = fmaxf(T3 + Kin[3], epsp);
        }
        abuf[(u+7)&7] += c0 * __logf(a0);
        abuf[(u+6)&7] += c1 * __logf(a1);
        abuf[(u+4)&7] += c2 * __logf(a2);
        abuf[u&7]     += c3 * __logf(a3);

        int ig = w0 - 15 + t;
        if (t >= 15 && ig <= w0 + 27) {
          float alpha = abuf[u&7];
          float a = alpha * scl + bofs;
          float sc = 0.f;
          #pragma unroll
          for (int k = 0; k < K; ++k)
            sc += fmaxf(0.f, 1.f - wd[k]*fabsf(a - anc[k]));
          float sig = 1.f / (1.f + __expf(-sc));
          float xv = __builtin_nontemporal_load(&xrow[ig*C]);
          __builtin_nontemporal_store(xv + sig, &orow[ig*C]);
        }
        abuf[u&7] = 0.f;
      }
    }
  };
  // interior iff every wr in [w0-7, w0+40] has full horizontal windows in-bounds
  if (w0 >= 22 && w0 <= 183) tloop(FalseT{}); else tloop(TrueT{});
}

// ================= FALLBACK PATH (verbatim R3 pipeline) =================

__global__ __launch_bounds__(256) void k_minmax_part(const float* __restrict__ x,
                                                     float* __restrict__ scratch) {
  int s   = blockIdx.x >> 9;
  int blk = blockIdx.x & 511;
  const float4* xs = (const float4*)(x + (size_t)s * HWC);
  const int n4 = HWC / 4;
  float vmin = INFINITY, vmax = -INFINITY;
  for (int i = blk*256 + threadIdx.x; i < n4; i += 512*256) {
    float4 v = xs[i];
    vmin = fminf(vmin, fminf(fminf(v.x, v.y), fminf(v.z, v.w)));
    vmax = fmaxf(vmax, fmaxf(fmaxf(v.x, v.y), fmaxf(v.z, v.w)));
  }
  __shared__ float smin[4], smax[4];
  float wmin = wave_reduce_min(vmin), wmax = wave_reduce_max(vmax);
  int wave = threadIdx.x >> 6, lane = threadIdx.x & 63;
  if (lane == 0) { smin[wave] = wmin; smax[wave] = wmax; }
  __syncthreads();
  if (threadIdx.x == 0) {
    float m = fminf(fminf(smin[0], smin[1]), fminf(smin[2], smin[3]));
    float M = fmaxf(fmaxf(smax[0], smax[1]), fmaxf(smax[2], smax[3]));
    scratch[blockIdx.x]        = m;
    scratch[2048 + blockIdx.x] = M;
  }
}

__global__ __launch_bounds__(256) void k_vpfx4(const float* __restrict__ x,
                                               const float* __restrict__ scratch,
                                               float* __restrict__ P) {
  int bid = blockIdx.x;
  int b = bid / W, w = bid % W;
  int seg = threadIdx.x >> 4;
  int chg = threadIdx.x & 15;
  int wv  = threadIdx.x >> 6;

  float vmn = fminf(scratch[b*512 + threadIdx.x], scratch[b*512 + 256 + threadIdx.x]);
  float vmx = fmaxf(scratch[2048 + b*512 + threadIdx.x], scratch[2048 + b*512 + 256 + threadIdx.x]);
  __shared__ float smin[4], smax[4];
  float wmn = wave_reduce_min(vmn), wmx = wave_reduce_max(vmx);
  if ((threadIdx.x & 63) == 0) { smin[wv] = wmn; smax[wv] = wmx; }
  __syncthreads();
  float xmin = fminf(fminf(smin[0], smin[1]), fminf(smin[2], smin[3]));
  float xmax = fmaxf(fmaxf(smax[0], smax[1]), fmaxf(smax[2], smax[3]));
  float inv  = 1.0f / (xmax - xmin + 1e-6f);

  const size_t colbase = (size_t)b*HWC + (size_t)w*C;
  const float4* xp4 = (const float4*)(x + colbase);
  const int RS4 = WC / 4;
  const int r0 = seg * 14;

  float4 v4[14];
  #pragma unroll
  for (int j = 0; j < 14; ++j) v4[j] = xp4[(size_t)(r0 + j) * RS4 + chg];

  float4 s4 = v4[0];
  #pragma unroll
  for (int j = 1; j < 14; ++j) {
    s4.x += v4[j].x; s4.y += v4[j].y; s4.z += v4[j].z; s4.w += v4[j].w;
  }

  __shared__ float4 segsum[16][16];
  segsum[seg][chg] = s4;
  __syncthreads();

  float4 o4 = {0.f, 0.f, 0.f, 0.f};
  #pragma unroll
  for (int ss = 0; ss < 16; ++ss) {
    if (ss < seg) {
      float4 t = segsum[ss][chg];
      o4.x += t.x; o4.y += t.y; o4.z += t.z; o4.w += t.w;
    }
  }

  float4* Pp4 = (float4*)(P + colbase);
  float ax = o4.x, ay = o4.y, az = o4.z, aw = o4.w;
  #pragma unroll
  for (int j = 0; j < 14; ++j) {
    ax += v4[j].x; ay += v4[j].y; az += v4[j].z; aw += v4[j].w;
    float sub = (float)(r0 + j + 1) * xmin;
    float4 outv;
    outv.x = (ax - sub) * inv;
    outv.y = (ay - sub) * inv;
    outv.z = (az - sub) * inv;
    outv.w = (aw - sub) * inv;
    Pp4[(size_t)(r0 + j) * RS4 + chg] = outv;
  }
}

__global__ __launch_bounds__(128) void k_main(
    const float* __restrict__ P, const float* __restrict__ x,
    const float* __restrict__ ols, const float* __restrict__ anchors,
    const float* __restrict__ hwidths, const float* __restrict__ bn_gamma,
    const float* __restrict__ bn_beta, const float* __restrict__ bn_mean,
    const float* __restrict__ bn_var, float* __restrict__ out) {
  int xcd  = blockIdx.x & 7;
  int i    = blockIdx.x >> 3;
  int rg   = xcd * 112 + (i >> 2);
  int wave = threadIdx.x >> 6, c = threadIdx.x & 63;
  int chunk = (i & 3) * 2 + wave;
  int b = rg / H, h = rg % H;
  int w0 = chunk * 28;

  const float LN2 = 0.69314718055994530942f;
  float wg0 = ols[0], wg1 = ols[1], wg2 = ols[2], wg3 = ols[3];
  float l0 = LN2, l1 = 2.f*LN2, l2 = 3.f*LN2, l3 = 4.f*LN2;
  float wsum = wg0 + wg1 + wg2 + wg3;
  float lrbar = (wg0*l0 + wg1*l1 + wg2*l2 + wg3*l3) / wsum;
  float d0 = l0-lrbar, d1 = l1-lrbar, d2 = l2-lrbar, d3 = l3-lrbar;
  float den = wg0*d0*d0 + wg1*d1*d1 + wg2*d2*d2 + wg3*d3*d3;
  float c0 = wg0*d0/den, c1 = wg1*d1/den, c2 = wg2*d2/den, c3 = wg3*d3/den;

  float scl  = bn_gamma[c] * rsqrtf(bn_var[c] + 1e-3f);
  float bofs = bn_beta[c] - bn_mean[c] * scl;
  float anc[K], wd[K];
  #pragma unroll
  for (int k = 0; k < K; ++k) { anc[k] = anchors[c*K + k]; wd[k] = hwidths[c*K + k]; }

  const int hiA[4] = {1, 2, 4, 8};
  const int loA[4] = {0, 1, 3, 7};
  const float* pt[4]; const float* pb[4]; float fb[4];
  #pragma unroll
  for (int s = 0; s < 4; ++s) {
    int ht = h + hiA[s]; if (ht > H-1) ht = H-1;
    int hb = h - loA[s] - 1;
    int hbc = hb < 0 ? 0 : hb;
    pt[s] = P + (size_t)b*HWC + (size_t)ht*WC + c;
    pb[s] = P + (size_t)b*HWC + (size_t)hbc*WC + c;
    fb[s] = hb < 0 ? 0.f : 1.f;
  }

  const float* xrow = x   + (size_t)b*HWC + (size_t)h*WC + c;
  float*       orow = out + (size_t)b*HWC + (size_t)h*WC + c;

  float ring2[2]   = {0,0};
  float ring4[4]   = {0,0,0,0};
  float ring8[8]   = {0,0,0,0,0,0,0,0};
  float ring16[16] = {0,0,0,0,0,0,0,0,0,0,0,0,0,0,0,0};
  float T0 = 0.f, T1 = 0.f, T2 = 0.f, T3 = 0.f;
  float abuf[8] = {0,0,0,0,0,0,0,0};

  for (int t0 = 0; t0 < 48; t0 += 16) {
    #pragma unroll
    for (int u = 0; u < 16; ++u) {
      int t  = t0 + u;
      int wr = w0 - 7 + t;
      float m0 = 0.f, m1 = 0.f, m2 = 0.f, m3 = 0.f;
      if (wr >= 0 && wr < W) {
        int off = wr * C;
        m0 = pt[0][off] - fb[0]*pb[0][off];
        m1 = pt[1][off] - fb[1]*pb[1][off];
        m2 = pt[2][off] - fb[2]*pb[2][off];
        m3 = pt[3][off] - fb[3]*pb[3][off];
      }
      T0 += m0 - ring2[u&1];  ring2[u&1]  = m0;
      T1 += m1 - ring4[u&3];  ring4[u&3]  = m1;
      T2 += m2 - ring8[u&7];  ring8[u&7]  = m2;
      T3 += m3 - ring16[u];   ring16[u]   = m3;
      abuf[(u+7)&7] += c0 * __logf(fmaxf(T0, 0.f) + 1e-6f);
      abuf[(u+6)&7] += c1 * __logf(fmaxf(T1, 0.f) + 1e-6f);
      abuf[(u+4)&7] += c2 * __logf(fmaxf(T2, 0.f) + 1e-6f);
      abuf[u&7]     += c3 * __logf(fmaxf(T3, 0.f) + 1e-6f);
      int ig = w0 - 15 + t;
      if (t >= 15 && ig <= w0 + 27) {
        float alpha = abuf[u&7];
        float a = alpha * scl + bofs;
        float sc = 0.f;
        #pragma unroll
        for (int k = 0; k < K; ++k)
          sc += fmaxf(0.f, 1.f - wd[k]*fabsf(a - anc[k]));
        float sig = 1.f / (1.f + __expf(-sc));
        float xv = __builtin_nontemporal_load(&xrow[ig*C]);
        __builtin_nontemporal_store(xv + sig, &orow[ig*C]);
      }
      abuf[u&7] = 0.f;
    }
  }
}

// ================================ host ================================

extern "C" void kernel_launch(void* const* d_in, const int* in_sizes, int n_in,
                              void* d_out, int out_size, void* d_ws, size_t ws_size,
                              hipStream_t stream) {
  const float* x        = (const float*)d_in[0];
  const float* ols      = (const float*)d_in[1];
  const float* anchors  = (const float*)d_in[2];
  const float* hwidths  = (const float*)d_in[3];
  const float* bn_gamma = (const float*)d_in[4];
  const float* bn_beta  = (const float*)d_in[5];
  const float* bn_mean  = (const float*)d_in[6];
  const float* bn_var   = (const float*)d_in[7];
  float* out = (float*)d_out;
  float* P   = (float*)d_ws;                      // B*H*W*C floats = 51.4 MB
  const size_t PBYTES = (size_t)B * HWC * sizeof(float);

  if (ws_size >= PBYTES + 8192) {
    // fast path: 2 kernels, single x pass in the producer, raw P + deferred norm
    float* pmn = (float*)((char*)d_ws + PBYTES);  // 896 used, 1024 reserved
    float* pmx = pmn + 1024;
    hipLaunchKernelGGL(k_vpfx_raw4, dim3(B*W),   dim3(256), 0, stream, x, P, pmn, pmx);
    hipLaunchKernelGGL(k_main2,     dim3(B*H*4), dim3(128), 0, stream,
                       P, x, pmn, pmx, ols, anchors, hwidths,
                       bn_gamma, bn_beta, bn_mean, bn_var, out);
  } else {
    // fallback: verbatim R3 3-kernel pipeline (scratch in d_out)
    float* scratch = out;
    hipLaunchKernelGGL(k_minmax_part, dim3(2048),  dim3(256), 0, stream, x, scratch);
    hipLaunchKernelGGL(k_vpfx4,       dim3(B*W),   dim3(256), 0, stream, x, scratch, P);
    hipLaunchKernelGGL(k_main,        dim3(B*H*4), dim3(128), 0, stream,
                       P, x, ols, anchors, hwidths,
                       bn_gamma, bn_beta, bn_mean, bn_var, out);
  }
}

// Round 7
// 223.370 us; speedup vs baseline: 1.0088x; 1.0088x over previous
//
#include <hip/hip_runtime.h>
#include <math.h>

#define B 4
#define H 224
#define W 224
#define C 64
#define K 8
#define WC (W*C)        // 14336
#define HWC (H*W*C)     // 3211264

__device__ inline float wave_reduce_min(float v) {
  #pragma unroll
  for (int off = 32; off > 0; off >>= 1)
    v = fminf(v, __shfl_down(v, off, 64));
  return v;
}
__device__ inline float wave_reduce_max(float v) {
  #pragma unroll
  for (int off = 32; off > 0; off >>= 1)
    v = fmaxf(v, __shfl_down(v, off, 64));
  return v;
}

struct FalseT { static constexpr bool value = false; };
struct TrueT  { static constexpr bool value = true; };

// ================= FAST PATH =================

// ---- Kernel A: wave-contiguous RAW column prefix sums + min/max partials ----
// R6 post-mortem: the (b,w)-block producer had each wave's load spanning 4
// h-rows x 256B scattered chunks -> ~1 TB/s cold. This remap makes every wave
// access 1024B contiguous (same shape as the 4 TB/s k_minmax_part):
//   block = (b, wg in [0,56)), 1024 threads = 16 h-segments x 64 float4-cols.
//   wave  = one segment, 64 consecutive float4s of one row.
// Math is verbatim from the verified producer (regs v4[14], segsum LDS
// exchange, carry, raw-P stores, inline min/max). Thread 0 writes its partial
// 4x so k_main2's 224-partial preamble stays byte-identical.
__global__ __launch_bounds__(1024) void k_vpfx_wide(const float* __restrict__ x,
                                                    float* __restrict__ P,
                                                    float* __restrict__ pmin,
                                                    float* __restrict__ pmax) {
  int bid = blockIdx.x;            // b*56 + wg
  int b  = bid / 56, wg = bid % 56;
  int tid  = threadIdx.x;
  int seg  = tid >> 6;             // [0,16) h-segment of 14 rows
  int lane = tid & 63;             // [0,64) float4-column within the strip
  int col4 = wg * 64 + lane;       // [0,3584) float4 index within a row

  const float4* x4 = (const float4*)x;
  float4*       P4 = (float4*)P;
  const size_t rowbase = (size_t)b * H;   // row index base for this sample
  const int r0 = seg * 14;

  // --- load 14 rows (1KB/wave contiguous); segment sums + min/max ---
  float4 v4[14];
  #pragma unroll
  for (int j = 0; j < 14; ++j)
    v4[j] = x4[(rowbase + r0 + j) * 3584 + col4];

  float4 s4 = v4[0];
  float vmin = fminf(fminf(v4[0].x, v4[0].y), fminf(v4[0].z, v4[0].w));
  float vmax = fmaxf(fmaxf(v4[0].x, v4[0].y), fmaxf(v4[0].z, v4[0].w));
  #pragma unroll
  for (int j = 1; j < 14; ++j) {
    s4.x += v4[j].x; s4.y += v4[j].y; s4.z += v4[j].z; s4.w += v4[j].w;
    vmin = fminf(vmin, fminf(fminf(v4[j].x, v4[j].y), fminf(v4[j].z, v4[j].w)));
    vmax = fmaxf(vmax, fmaxf(fmaxf(v4[j].x, v4[j].y), fmaxf(v4[j].z, v4[j].w)));
  }

  __shared__ float4 segsum[16][64];   // [seg][lane]
  __shared__ float smin[16], smax[16];
  segsum[seg][lane] = s4;
  float wmn = wave_reduce_min(vmin), wmx = wave_reduce_max(vmax);
  if (lane == 0) { smin[seg] = wmn; smax[seg] = wmx; }
  __syncthreads();

  if (tid == 0) {
    float m = smin[0], M = smax[0];
    #pragma unroll
    for (int s = 1; s < 16; ++s) { m = fminf(m, smin[s]); M = fmaxf(M, smax[s]); }
    int base = b * 224 + wg * 4;    // 4 duplicate slots -> 224 partials/sample,
    pmin[base+0] = m; pmin[base+1] = m; pmin[base+2] = m; pmin[base+3] = m;
    pmax[base+0] = M; pmax[base+1] = M; pmax[base+2] = M; pmax[base+3] = M;
  }

  // Offset = sum of earlier segments for this column (broadcast-free reads)
  float4 o4 = {0.f, 0.f, 0.f, 0.f};
  #pragma unroll
  for (int ss = 0; ss < 16; ++ss) {
    if (ss < seg) {
      float4 t = segsum[ss][lane];
      o4.x += t.x; o4.y += t.y; o4.z += t.z; o4.w += t.w;
    }
  }

  // --- RAW prefix write (1KB/wave contiguous) ---
  float ax = o4.x, ay = o4.y, az = o4.z, aw = o4.w;
  #pragma unroll
  for (int j = 0; j < 14; ++j) {
    ax += v4[j].x; ay += v4[j].y; az += v4[j].z; aw += v4[j].w;
    float4 outv; outv.x = ax; outv.y = ay; outv.z = az; outv.w = aw;
    P4[(rowbase + r0 + j) * 3584 + col4] = outv;
  }
}

// ---- Kernel B: VERBATIM R1/R6 k_main2 (deferred normalization; verified) ----
__global__ __launch_bounds__(128) void k_main2(
    const float* __restrict__ P, const float* __restrict__ x,
    const float* __restrict__ pmin, const float* __restrict__ pmax,
    const float* __restrict__ ols, const float* __restrict__ anchors,
    const float* __restrict__ hwidths, const float* __restrict__ bn_gamma,
    const float* __restrict__ bn_beta, const float* __restrict__ bn_mean,
    const float* __restrict__ bn_var, float* __restrict__ out) {
  int xcd  = blockIdx.x & 7;
  int i    = blockIdx.x >> 3;        // [0,448)
  int rg   = xcd * 112 + (i >> 2);   // global row in [0,896)
  int wave = threadIdx.x >> 6, c = threadIdx.x & 63;
  int chunk = (i & 3) * 2 + wave;    // [0,8)
  int b = rg / H, h = rg % H;
  int w0 = chunk * 28;

  // --- finalize per-sample min/max from 224 partials (L2-hot) ---
  float vmin = INFINITY, vmax = -INFINITY;
  for (int ii = threadIdx.x; ii < W; ii += 128) {
    vmin = fminf(vmin, pmin[b*W + ii]);
    vmax = fmaxf(vmax, pmax[b*W + ii]);
  }
  vmin = wave_reduce_min(vmin);
  vmax = wave_reduce_max(vmax);
  __shared__ float sred[4];
  if ((threadIdx.x & 63) == 0) { sred[wave*2] = vmin; sred[wave*2+1] = vmax; }
  __syncthreads();
  float xmin = fminf(sred[0], sred[2]);
  float xmax = fmaxf(sred[1], sred[3]);
  float rng  = xmax - xmin + 1e-6f;
  float epsp = 1e-6f * rng;          // eps lifted to the unnormalized domain

  const float LN2 = 0.69314718055994530942f;
  float wg0 = ols[0], wg1 = ols[1], wg2 = ols[2], wg3 = ols[3];
  float l0 = LN2, l1 = 2.f*LN2, l2 = 3.f*LN2, l3 = 4.f*LN2;
  float wsum = wg0 + wg1 + wg2 + wg3;
  float lrbar = (wg0*l0 + wg1*l1 + wg2*l2 + wg3*l3) / wsum;
  float d0 = l0-lrbar, d1 = l1-lrbar, d2 = l2-lrbar, d3 = l3-lrbar;
  float den = wg0*d0*d0 + wg1*d1*d1 + wg2*d2*d2 + wg3*d3*d3;
  float c0 = wg0*d0/den, c1 = wg1*d1/den, c2 = wg2*d2/den, c3 = wg3*d3/den;

  float scl  = bn_gamma[c] * rsqrtf(bn_var[c] + 1e-3f);
  float bofs = bn_beta[c] - bn_mean[c] * scl;
  float anc[K], wd[K];
  #pragma unroll
  for (int k = 0; k < K; ++k) { anc[k] = anchors[c*K + k]; wd[k] = hwidths[c*K + k]; }

  const int hiA[4] = {1, 2, 4, 8};
  const int loA[4] = {0, 1, 3, 7};
  const int rA[4]  = {2, 4, 8, 16};
  const float* pt[4]; const float* pb[4]; float fb[4];
  float Anh[4], Kin[4];
  #pragma unroll
  for (int s = 0; s < 4; ++s) {
    int ht = h + hiA[s]; if (ht > H-1) ht = H-1;
    int hb = h - loA[s] - 1;
    int hbc = hb < 0 ? 0 : hb;
    pt[s] = P + (size_t)b*HWC + (size_t)ht*WC + c;
    pb[s] = P + (size_t)b*HWC + (size_t)hbc*WC + c;
    fb[s] = hb < 0 ? 0.f : 1.f;
    int h0 = h - loA[s]; if (h0 < 0) h0 = 0;
    int nv = ht - h0 + 1;              // in-bounds rows of the vertical window
    Anh[s] = -(float)nv * xmin;        // per-column xmin correction factor
    Kin[s] = (float)rA[s] * Anh[s] + epsp;   // interior: nh == r, eps folded
  }

  const float* xrow = x   + (size_t)b*HWC + (size_t)h*WC + c;
  float*       orow = out + (size_t)b*HWC + (size_t)h*WC + c;

  auto tloop = [&](auto EDGEC) {
    constexpr bool EDGE = decltype(EDGEC)::value;
    float ring2[2]   = {0,0};
    float ring4[4]   = {0,0,0,0};
    float ring8[8]   = {0,0,0,0,0,0,0,0};
    float ring16[16] = {0,0,0,0,0,0,0,0,0,0,0,0,0,0,0,0};
    float T0 = 0.f, T1 = 0.f, T2 = 0.f, T3 = 0.f;
    float abuf[8] = {0,0,0,0,0,0,0,0};

    for (int t0 = 0; t0 < 48; t0 += 16) {
      #pragma unroll
      for (int u = 0; u < 16; ++u) {
        int t  = t0 + u;
        int wr = w0 - 7 + t;
        float m0, m1, m2, m3;
        if constexpr (EDGE) {
          m0 = m1 = m2 = m3 = 0.f;
          if (wr >= 0 && wr < W) {
            int off = wr * C;
            m0 = pt[0][off] - fb[0]*pb[0][off];
            m1 = pt[1][off] - fb[1]*pb[1][off];
            m2 = pt[2][off] - fb[2]*pb[2][off];
            m3 = pt[3][off] - fb[3]*pb[3][off];
          }
        } else {
          int off = wr * C;
          m0 = pt[0][off] - fb[0]*pb[0][off];
          m1 = pt[1][off] - fb[1]*pb[1][off];
          m2 = pt[2][off] - fb[2]*pb[2][off];
          m3 = pt[3][off] - fb[3]*pb[3][off];
        }
        T0 += m0 - ring2[u&1];  ring2[u&1]  = m0;
        T1 += m1 - ring4[u&3];  ring4[u&3]  = m1;
        T2 += m2 - ring8[u&7];  ring8[u&7]  = m2;
        T3 += m3 - ring16[u];   ring16[u]   = m3;

        float a0, a1, a2, a3;
        if constexpr (EDGE) {
          float nh0 = (float)(min(wr, W-1) - max(wr-1,  0) + 1);
          float nh1 = (float)(min(wr, W-1) - max(wr-3,  0) + 1);
          float nh2 = (float)(min(wr, W-1) - max(wr-7,  0) + 1);
          float nh3 = (float)(min(wr, W-1) - max(wr-15, 0) + 1);
          a0 = fmaxf(fmaf(Anh[0], nh0, T0) + epsp, epsp);
          a1 = fmaxf(fmaf(Anh[1], nh1, T1) + epsp, epsp);
          a2 = fmaxf(fmaf(Anh[2], nh2, T2) + epsp, epsp);
          a3 = fmaxf(fmaf(Anh[3], nh3, T3) + epsp, epsp);
        } else {
          a0 = fmaxf(T0 + Kin[0], epsp);
          a1 = fmaxf(T1 + Kin[1], epsp);
          a2 = fmaxf(T2 + Kin[2], epsp);
          a3 = fmaxf(T3 + Kin[3], epsp);
        }
        abuf[(u+7)&7] += c0 * __logf(a0);
        abuf[(u+6)&7] += c1 * __logf(a1);
        abuf[(u+4)&7] += c2 * __logf(a2);
        abuf[u&7]     += c3 * __logf(a3);

        int ig = w0 - 15 + t;
        if (t >= 15 && ig <= w0 + 27) {
          float alpha = abuf[u&7];
          float a = alpha * scl + bofs;
          float sc = 0.f;
          #pragma unroll
          for (int k = 0; k < K; ++k)
            sc += fmaxf(0.f, 1.f - wd[k]*fabsf(a - anc[k]));
          float sig = 1.f / (1.f + __expf(-sc));
          float xv = __builtin_nontemporal_load(&xrow[ig*C]);
          __builtin_nontemporal_store(xv + sig, &orow[ig*C]);
        }
        abuf[u&7] = 0.f;
      }
    }
  };
  // interior iff every wr in [w0-7, w0+40] has full horizontal windows in-bounds
  if (w0 >= 22 && w0 <= 183) tloop(FalseT{}); else tloop(TrueT{});
}

// ================= FALLBACK PATH (verbatim R3 pipeline) =================

__global__ __launch_bounds__(256) void k_minmax_part(const float* __restrict__ x,
                                                     float* __restrict__ scratch) {
  int s   = blockIdx.x >> 9;
  int blk = blockIdx.x & 511;
  const float4* xs = (const float4*)(x + (size_t)s * HWC);
  const int n4 = HWC / 4;
  float vmin = INFINITY, vmax = -INFINITY;
  for (int i = blk*256 + threadIdx.x; i < n4; i += 512*256) {
    float4 v = xs[i];
    vmin = fminf(vmin, fminf(fminf(v.x, v.y), fminf(v.z, v.w)));
    vmax = fmaxf(vmax, fmaxf(fmaxf(v.x, v.y), fmaxf(v.z, v.w)));
  }
  __shared__ float smin[4], smax[4];
  float wmin = wave_reduce_min(vmin), wmax = wave_reduce_max(vmax);
  int wave = threadIdx.x >> 6, lane = threadIdx.x & 63;
  if (lane == 0) { smin[wave] = wmin; smax[wave] = wmax; }
  __syncthreads();
  if (threadIdx.x == 0) {
    float m = fminf(fminf(smin[0], smin[1]), fminf(smin[2], smin[3]));
    float M = fmaxf(fmaxf(smax[0], smax[1]), fmaxf(smax[2], smax[3]));
    scratch[blockIdx.x]        = m;
    scratch[2048 + blockIdx.x] = M;
  }
}

__global__ __launch_bounds__(256) void k_vpfx4(const float* __restrict__ x,
                                               const float* __restrict__ scratch,
                                               float* __restrict__ P) {
  int bid = blockIdx.x;
  int b = bid / W, w = bid % W;
  int seg = threadIdx.x >> 4;
  int chg = threadIdx.x & 15;
  int wv  = threadIdx.x >> 6;

  float vmn = fminf(scratch[b*512 + threadIdx.x], scratch[b*512 + 256 + threadIdx.x]);
  float vmx = fmaxf(scratch[2048 + b*512 + threadIdx.x], scratch[2048 + b*512 + 256 + threadIdx.x]);
  __shared__ float smin[4], smax[4];
  float wmn = wave_reduce_min(vmn), wmx = wave_reduce_max(vmx);
  if ((threadIdx.x & 63) == 0) { smin[wv] = wmn; smax[wv] = wmx; }
  __syncthreads();
  float xmin = fminf(fminf(smin[0], smin[1]), fminf(smin[2], smin[3]));
  float xmax = fmaxf(fmaxf(smax[0], smax[1]), fmaxf(smax[2], smax[3]));
  float inv  = 1.0f / (xmax - xmin + 1e-6f);

  const size_t colbase = (size_t)b*HWC + (size_t)w*C;
  const float4* xp4 = (const float4*)(x + colbase);
  const int RS4 = WC / 4;
  const int r0 = seg * 14;

  float4 v4[14];
  #pragma unroll
  for (int j = 0; j < 14; ++j) v4[j] = xp4[(size_t)(r0 + j) * RS4 + chg];

  float4 s4 = v4[0];
  #pragma unroll
  for (int j = 1; j < 14; ++j) {
    s4.x += v4[j].x; s4.y += v4[j].y; s4.z += v4[j].z; s4.w += v4[j].w;
  }

  __shared__ float4 segsum[16][16];
  segsum[seg][chg] = s4;
  __syncthreads();

  float4 o4 = {0.f, 0.f, 0.f, 0.f};
  #pragma unroll
  for (int ss = 0; ss < 16; ++ss) {
    if (ss < seg) {
      float4 t = segsum[ss][chg];
      o4.x += t.x; o4.y += t.y; o4.z += t.z; o4.w += t.w;
    }
  }

  float4* Pp4 = (float4*)(P + colbase);
  float ax = o4.x, ay = o4.y, az = o4.z, aw = o4.w;
  #pragma unroll
  for (int j = 0; j < 14; ++j) {
    ax += v4[j].x; ay += v4[j].y; az += v4[j].z; aw += v4[j].w;
    float sub = (float)(r0 + j + 1) * xmin;
    float4 outv;
    outv.x = (ax - sub) * inv;
    outv.y = (ay - sub) * inv;
    outv.z = (az - sub) * inv;
    outv.w = (aw - sub) * inv;
    Pp4[(size_t)(r0 + j) * RS4 + chg] = outv;
  }
}

__global__ __launch_bounds__(128) void k_main(
    const float* __restrict__ P, const float* __restrict__ x,
    const float* __restrict__ ols, const float* __restrict__ anchors,
    const float* __restrict__ hwidths, const float* __restrict__ bn_gamma,
    const float* __restrict__ bn_beta, const float* __restrict__ bn_mean,
    const float* __restrict__ bn_var, float* __restrict__ out) {
  int xcd  = blockIdx.x & 7;
  int i    = blockIdx.x >> 3;
  int rg   = xcd * 112 + (i >> 2);
  int wave = threadIdx.x >> 6, c = threadIdx.x & 63;
  int chunk = (i & 3) * 2 + wave;
  int b = rg / H, h = rg % H;
  int w0 = chunk * 28;

  const float LN2 = 0.69314718055994530942f;
  float wg0 = ols[0], wg1 = ols[1], wg2 = ols[2], wg3 = ols[3];
  float l0 = LN2, l1 = 2.f*LN2, l2 = 3.f*LN2, l3 = 4.f*LN2;
  float wsum = wg0 + wg1 + wg2 + wg3;
  float lrbar = (wg0*l0 + wg1*l1 + wg2*l2 + wg3*l3) / wsum;
  float d0 = l0-lrbar, d1 = l1-lrbar, d2 = l2-lrbar, d3 = l3-lrbar;
  float den = wg0*d0*d0 + wg1*d1*d1 + wg2*d2*d2 + wg3*d3*d3;
  float c0 = wg0*d0/den, c1 = wg1*d1/den, c2 = wg2*d2/den, c3 = wg3*d3/den;

  float scl  = bn_gamma[c] * rsqrtf(bn_var[c] + 1e-3f);
  float bofs = bn_beta[c] - bn_mean[c] * scl;
  float anc[K], wd[K];
  #pragma unroll
  for (int k = 0; k < K; ++k) { anc[k] = anchors[c*K + k]; wd[k] = hwidths[c*K + k]; }

  const int hiA[4] = {1, 2, 4, 8};
  const int loA[4] = {0, 1, 3, 7};
  const float* pt[4]; const float* pb[4]; float fb[4];
  #pragma unroll
  for (int s = 0; s < 4; ++s) {
    int ht = h + hiA[s]; if (ht > H-1) ht = H-1;
    int hb = h - loA[s] - 1;
    int hbc = hb < 0 ? 0 : hb;
    pt[s] = P + (size_t)b*HWC + (size_t)ht*WC + c;
    pb[s] = P + (size_t)b*HWC + (size_t)hbc*WC + c;
    fb[s] = hb < 0 ? 0.f : 1.f;
  }

  const float* xrow = x   + (size_t)b*HWC + (size_t)h*WC + c;
  float*       orow = out + (size_t)b*HWC + (size_t)h*WC + c;

  float ring2[2]   = {0,0};
  float ring4[4]   = {0,0,0,0};
  float ring8[8]   = {0,0,0,0,0,0,0,0};
  float ring16[16] = {0,0,0,0,0,0,0,0,0,0,0,0,0,0,0,0};
  float T0 = 0.f, T1 = 0.f, T2 = 0.f, T3 = 0.f;
  float abuf[8] = {0,0,0,0,0,0,0,0};

  for (int t0 = 0; t0 < 48; t0 += 16) {
    #pragma unroll
    for (int u = 0; u < 16; ++u) {
      int t  = t0 + u;
      int wr = w0 - 7 + t;
      float m0 = 0.f, m1 = 0.f, m2 = 0.f, m3 = 0.f;
      if (wr >= 0 && wr < W) {
        int off = wr * C;
        m0 = pt[0][off] - fb[0]*pb[0][off];
        m1 = pt[1][off] - fb[1]*pb[1][off];
        m2 = pt[2][off] - fb[2]*pb[2][off];
        m3 = pt[3][off] - fb[3]*pb[3][off];
      }
      T0 += m0 - ring2[u&1];  ring2[u&1]  = m0;
      T1 += m1 - ring4[u&3];  ring4[u&3]  = m1;
      T2 += m2 - ring8[u&7];  ring8[u&7]  = m2;
      T3 += m3 - ring16[u];   ring16[u]   = m3;
      abuf[(u+7)&7] += c0 * __logf(fmaxf(T0, 0.f) + 1e-6f);
      abuf[(u+6)&7] += c1 * __logf(fmaxf(T1, 0.f) + 1e-6f);
      abuf[(u+4)&7] += c2 * __logf(fmaxf(T2, 0.f) + 1e-6f);
      abuf[u&7]     += c3 * __logf(fmaxf(T3, 0.f) + 1e-6f);
      int ig = w0 - 15 + t;
      if (t >= 15 && ig <= w0 + 27) {
        float alpha = abuf[u&7];
        float a = alpha * scl + bofs;
        float sc = 0.f;
        #pragma unroll
        for (int k = 0; k < K; ++k)
          sc += fmaxf(0.f, 1.f - wd[k]*fabsf(a - anc[k]));
        float sig = 1.f / (1.f + __expf(-sc));
        float xv = __builtin_nontemporal_load(&xrow[ig*C]);
        __builtin_nontemporal_store(xv + sig, &orow[ig*C]);
      }
      abuf[u&7] = 0.f;
    }
  }
}

// ================================ host ================================

extern "C" void kernel_launch(void* const* d_in, const int* in_sizes, int n_in,
                              void* d_out, int out_size, void* d_ws, size_t ws_size,
                              hipStream_t stream) {
  const float* x        = (const float*)d_in[0];
  const float* ols      = (const float*)d_in[1];
  const float* anchors  = (const float*)d_in[2];
  const float* hwidths  = (const float*)d_in[3];
  const float* bn_gamma = (const float*)d_in[4];
  const float* bn_beta  = (const float*)d_in[5];
  const float* bn_mean  = (const float*)d_in[6];
  const float* bn_var   = (const float*)d_in[7];
  float* out = (float*)d_out;
  float* P   = (float*)d_ws;                      // B*H*W*C floats = 51.4 MB
  const size_t PBYTES = (size_t)B * HWC * sizeof(float);

  if (ws_size >= PBYTES + 8192) {
    // fast path: wave-contiguous single-pass producer + deferred-norm consumer
    float* pmn = (float*)((char*)d_ws + PBYTES);  // 896 used, 1024 reserved
    float* pmx = pmn + 1024;
    hipLaunchKernelGGL(k_vpfx_wide, dim3(B*56),  dim3(1024), 0, stream, x, P, pmn, pmx);
    hipLaunchKernelGGL(k_main2,     dim3(B*H*4), dim3(128),  0, stream,
                       P, x, pmn, pmx, ols, anchors, hwidths,
                       bn_gamma, bn_beta, bn_mean, bn_var, out);
  } else {
    // fallback: verbatim R3 3-kernel pipeline (scratch in d_out)
    float* scratch = out;
    hipLaunchKernelGGL(k_minmax_part, dim3(2048),  dim3(256), 0, stream, x, scratch);
    hipLaunchKernelGGL(k_vpfx4,       dim3(B*W),   dim3(256), 0, stream, x, scratch, P);
    hipLaunchKernelGGL(k_main,        dim3(B*H*4), dim3(128), 0, stream,
                       P, x, ols, anchors, hwidths,
                       bn_gamma, bn_beta, bn_mean, bn_var, out);
  }
}

// Round 8
// 211.459 us; speedup vs baseline: 1.0656x; 1.0563x over previous
//
#include <hip/hip_runtime.h>
#include <math.h>

#define B 4
#define H 224
#define W 224
#define C 64
#define K 8
#define WC (W*C)        // 14336
#define HWC (H*W*C)     // 3211264

__device__ inline float wave_reduce_min(float v) {
  #pragma unroll
  for (int off = 32; off > 0; off >>= 1)
    v = fminf(v, __shfl_down(v, off, 64));
  return v;
}
__device__ inline float wave_reduce_max(float v) {
  #pragma unroll
  for (int off = 32; off > 0; off >>= 1)
    v = fmaxf(v, __shfl_down(v, off, 64));
  return v;
}

struct FalseT { static constexpr bool value = false; };
struct TrueT  { static constexpr bool value = true; };

// ================= FAST PATH =================

// ---- Kernel A: VERBATIM R7 producer (wave-contiguous raw prefix + partials) --
__global__ __launch_bounds__(1024) void k_vpfx_wide(const float* __restrict__ x,
                                                    float* __restrict__ P,
                                                    float* __restrict__ pmin,
                                                    float* __restrict__ pmax) {
  int bid = blockIdx.x;            // b*56 + wg
  int b  = bid / 56, wg = bid % 56;
  int tid  = threadIdx.x;
  int seg  = tid >> 6;             // [0,16) h-segment of 14 rows
  int lane = tid & 63;             // [0,64) float4-column within the strip
  int col4 = wg * 64 + lane;       // [0,3584) float4 index within a row

  const float4* x4 = (const float4*)x;
  float4*       P4 = (float4*)P;
  const size_t rowbase = (size_t)b * H;
  const int r0 = seg * 14;

  float4 v4[14];
  #pragma unroll
  for (int j = 0; j < 14; ++j)
    v4[j] = x4[(rowbase + r0 + j) * 3584 + col4];

  float4 s4 = v4[0];
  float vmin = fminf(fminf(v4[0].x, v4[0].y), fminf(v4[0].z, v4[0].w));
  float vmax = fmaxf(fmaxf(v4[0].x, v4[0].y), fmaxf(v4[0].z, v4[0].w));
  #pragma unroll
  for (int j = 1; j < 14; ++j) {
    s4.x += v4[j].x; s4.y += v4[j].y; s4.z += v4[j].z; s4.w += v4[j].w;
    vmin = fminf(vmin, fminf(fminf(v4[j].x, v4[j].y), fminf(v4[j].z, v4[j].w)));
    vmax = fmaxf(vmax, fmaxf(fmaxf(v4[j].x, v4[j].y), fmaxf(v4[j].z, v4[j].w)));
  }

  __shared__ float4 segsum[16][64];
  __shared__ float smin[16], smax[16];
  segsum[seg][lane] = s4;
  float wmn = wave_reduce_min(vmin), wmx = wave_reduce_max(vmax);
  if (lane == 0) { smin[seg] = wmn; smax[seg] = wmx; }
  __syncthreads();

  if (tid == 0) {
    float m = smin[0], M = smax[0];
    #pragma unroll
    for (int s = 1; s < 16; ++s) { m = fminf(m, smin[s]); M = fmaxf(M, smax[s]); }
    int base = b * 224 + wg * 4;
    pmin[base+0] = m; pmin[base+1] = m; pmin[base+2] = m; pmin[base+3] = m;
    pmax[base+0] = M; pmax[base+1] = M; pmax[base+2] = M; pmax[base+3] = M;
  }

  float4 o4 = {0.f, 0.f, 0.f, 0.f};
  #pragma unroll
  for (int ss = 0; ss < 16; ++ss) {
    if (ss < seg) {
      float4 t = segsum[ss][lane];
      o4.x += t.x; o4.y += t.y; o4.z += t.z; o4.w += t.w;
    }
  }

  float ax = o4.x, ay = o4.y, az = o4.z, aw = o4.w;
  #pragma unroll
  for (int j = 0; j < 14; ++j) {
    ax += v4[j].x; ay += v4[j].y; az += v4[j].z; aw += v4[j].w;
    float4 outv; outv.x = ax; outv.y = ay; outv.z = az; outv.w = aw;
    P4[(rowbase + r0 + j) * 3584 + col4] = outv;
  }
}

// ---- Kernel B: k_main2 with 56-wide chunks (R8 geometry change) ----
// Inner-body arithmetic VERBATIM from the verified k_main2. Only the chunk
// geometry changed: 4 waves/row x 56 outputs (80 steps) instead of
// 8 waves/row x 28 outputs (64 steps) -> total wave-steps 458k -> 287k
// (0.625x): warmup amortized over 2x the columns. Ring/abuf indices stay
// compile-time (unroll 16, t0 multiple of 16). Interior = w0 in {56,112}
// (full 16-windows for all t<72; unchecked loads in-bounds for all t<80).
__global__ __launch_bounds__(128) void k_main2(
    const float* __restrict__ P, const float* __restrict__ x,
    const float* __restrict__ pmin, const float* __restrict__ pmax,
    const float* __restrict__ ols, const float* __restrict__ anchors,
    const float* __restrict__ hwidths, const float* __restrict__ bn_gamma,
    const float* __restrict__ bn_beta, const float* __restrict__ bn_mean,
    const float* __restrict__ bn_var, float* __restrict__ out) {
  int xcd  = blockIdx.x & 7;
  int i    = blockIdx.x >> 3;        // [0,224)
  int rg   = xcd * 112 + (i >> 1);   // global row in [0,896)
  int wave = threadIdx.x >> 6, c = threadIdx.x & 63;
  int chunk = (i & 1) * 2 + wave;    // [0,4)
  int b = rg / H, h = rg % H;
  int w0 = chunk * 56;

  // --- finalize per-sample min/max from 224 partials (L2-hot) ---
  float vmin = INFINITY, vmax = -INFINITY;
  for (int ii = threadIdx.x; ii < W; ii += 128) {
    vmin = fminf(vmin, pmin[b*W + ii]);
    vmax = fmaxf(vmax, pmax[b*W + ii]);
  }
  vmin = wave_reduce_min(vmin);
  vmax = wave_reduce_max(vmax);
  __shared__ float sred[4];
  if ((threadIdx.x & 63) == 0) { sred[wave*2] = vmin; sred[wave*2+1] = vmax; }
  __syncthreads();
  float xmin = fminf(sred[0], sred[2]);
  float xmax = fmaxf(sred[1], sred[3]);
  float rng  = xmax - xmin + 1e-6f;
  float epsp = 1e-6f * rng;          // eps lifted to the unnormalized domain

  const float LN2 = 0.69314718055994530942f;
  float wg0 = ols[0], wg1 = ols[1], wg2 = ols[2], wg3 = ols[3];
  float l0 = LN2, l1 = 2.f*LN2, l2 = 3.f*LN2, l3 = 4.f*LN2;
  float wsum = wg0 + wg1 + wg2 + wg3;
  float lrbar = (wg0*l0 + wg1*l1 + wg2*l2 + wg3*l3) / wsum;
  float d0 = l0-lrbar, d1 = l1-lrbar, d2 = l2-lrbar, d3 = l3-lrbar;
  float den = wg0*d0*d0 + wg1*d1*d1 + wg2*d2*d2 + wg3*d3*d3;
  float c0 = wg0*d0/den, c1 = wg1*d1/den, c2 = wg2*d2/den, c3 = wg3*d3/den;

  float scl  = bn_gamma[c] * rsqrtf(bn_var[c] + 1e-3f);
  float bofs = bn_beta[c] - bn_mean[c] * scl;
  float anc[K], wd[K];
  #pragma unroll
  for (int k = 0; k < K; ++k) { anc[k] = anchors[c*K + k]; wd[k] = hwidths[c*K + k]; }

  const int hiA[4] = {1, 2, 4, 8};
  const int loA[4] = {0, 1, 3, 7};
  const int rA[4]  = {2, 4, 8, 16};
  const float* pt[4]; const float* pb[4]; float fb[4];
  float Anh[4], Kin[4];
  #pragma unroll
  for (int s = 0; s < 4; ++s) {
    int ht = h + hiA[s]; if (ht > H-1) ht = H-1;
    int hb = h - loA[s] - 1;
    int hbc = hb < 0 ? 0 : hb;
    pt[s] = P + (size_t)b*HWC + (size_t)ht*WC + c;
    pb[s] = P + (size_t)b*HWC + (size_t)hbc*WC + c;
    fb[s] = hb < 0 ? 0.f : 1.f;
    int h0 = h - loA[s]; if (h0 < 0) h0 = 0;
    int nv = ht - h0 + 1;              // in-bounds rows of the vertical window
    Anh[s] = -(float)nv * xmin;        // per-column xmin correction factor
    Kin[s] = (float)rA[s] * Anh[s] + epsp;   // interior: nh == r, eps folded
  }

  const float* xrow = x   + (size_t)b*HWC + (size_t)h*WC + c;
  float*       orow = out + (size_t)b*HWC + (size_t)h*WC + c;

  auto tloop = [&](auto EDGEC) {
    constexpr bool EDGE = decltype(EDGEC)::value;
    float ring2[2]   = {0,0};
    float ring4[4]   = {0,0,0,0};
    float ring8[8]   = {0,0,0,0,0,0,0,0};
    float ring16[16] = {0,0,0,0,0,0,0,0,0,0,0,0,0,0,0,0};
    float T0 = 0.f, T1 = 0.f, T2 = 0.f, T3 = 0.f;
    float abuf[8] = {0,0,0,0,0,0,0,0};

    for (int t0 = 0; t0 < 80; t0 += 16) {      // 80 steps: 15 warmup + 56 out + pad
      #pragma unroll
      for (int u = 0; u < 16; ++u) {
        int t  = t0 + u;
        int wr = w0 - 7 + t;
        float m0, m1, m2, m3;
        if constexpr (EDGE) {
          m0 = m1 = m2 = m3 = 0.f;
          if (wr >= 0 && wr < W) {
            int off = wr * C;
            m0 = pt[0][off] - fb[0]*pb[0][off];
            m1 = pt[1][off] - fb[1]*pb[1][off];
            m2 = pt[2][off] - fb[2]*pb[2][off];
            m3 = pt[3][off] - fb[3]*pb[3][off];
          }
        } else {
          int off = wr * C;
          m0 = pt[0][off] - fb[0]*pb[0][off];
          m1 = pt[1][off] - fb[1]*pb[1][off];
          m2 = pt[2][off] - fb[2]*pb[2][off];
          m3 = pt[3][off] - fb[3]*pb[3][off];
        }
        T0 += m0 - ring2[u&1];  ring2[u&1]  = m0;
        T1 += m1 - ring4[u&3];  ring4[u&3]  = m1;
        T2 += m2 - ring8[u&7];  ring8[u&7]  = m2;
        T3 += m3 - ring16[u];   ring16[u]   = m3;

        float a0, a1, a2, a3;
        if constexpr (EDGE) {
          float nh0 = (float)(min(wr, W-1) - max(wr-1,  0) + 1);
          float nh1 = (float)(min(wr, W-1) - max(wr-3,  0) + 1);
          float nh2 = (float)(min(wr, W-1) - max(wr-7,  0) + 1);
          float nh3 = (float)(min(wr, W-1) - max(wr-15, 0) + 1);
          a0 = fmaxf(fmaf(Anh[0], nh0, T0) + epsp, epsp);
          a1 = fmaxf(fmaf(Anh[1], nh1, T1) + epsp, epsp);
          a2 = fmaxf(fmaf(Anh[2], nh2, T2) + epsp, epsp);
          a3 = fmaxf(fmaf(Anh[3], nh3, T3) + epsp, epsp);
        } else {
          a0 = fmaxf(T0 + Kin[0], epsp);
          a1 = fmaxf(T1 + Kin[1], epsp);
          a2 = fmaxf(T2 + Kin[2], epsp);
          a3 = fmaxf(T3 + Kin[3], epsp);
        }
        abuf[(u+7)&7] += c0 * __logf(a0);
        abuf[(u+6)&7] += c1 * __logf(a1);
        abuf[(u+4)&7] += c2 * __logf(a2);
        abuf[u&7]     += c3 * __logf(a3);

        int ig = w0 - 15 + t;
        if (t >= 15 && t <= 70) {              // ig in [w0, w0+55]
          float alpha = abuf[u&7];
          float a = alpha * scl + bofs;
          float sc = 0.f;
          #pragma unroll
          for (int k = 0; k < K; ++k)
            sc += fmaxf(0.f, 1.f - wd[k]*fabsf(a - anc[k]));
          float sig = 1.f / (1.f + __expf(-sc));
          float xv = __builtin_nontemporal_load(&xrow[ig*C]);
          __builtin_nontemporal_store(xv + sig, &orow[ig*C]);
        }
        abuf[u&7] = 0.f;
      }
    }
  };
  // interior iff full 16-wide windows for every contributing step (w0>=22)
  // and unchecked loads in-bounds for all t<80 (w0+72 <= 223 -> w0 <= 151)
  if (w0 >= 22 && w0 <= 151) tloop(FalseT{}); else tloop(TrueT{});
}

// ================= FALLBACK PATH (verbatim R3 pipeline) =================

__global__ __launch_bounds__(256) void k_minmax_part(const float* __restrict__ x,
                                                     float* __restrict__ scratch) {
  int s   = blockIdx.x >> 9;
  int blk = blockIdx.x & 511;
  const float4* xs = (const float4*)(x + (size_t)s * HWC);
  const int n4 = HWC / 4;
  float vmin = INFINITY, vmax = -INFINITY;
  for (int i = blk*256 + threadIdx.x; i < n4; i += 512*256) {
    float4 v = xs[i];
    vmin = fminf(vmin, fminf(fminf(v.x, v.y), fminf(v.z, v.w)));
    vmax = fmaxf(vmax, fmaxf(fmaxf(v.x, v.y), fmaxf(v.z, v.w)));
  }
  __shared__ float smin[4], smax[4];
  float wmin = wave_reduce_min(vmin), wmax = wave_reduce_max(vmax);
  int wave = threadIdx.x >> 6, lane = threadIdx.x & 63;
  if (lane == 0) { smin[wave] = wmin; smax[wave] = wmax; }
  __syncthreads();
  if (threadIdx.x == 0) {
    float m = fminf(fminf(smin[0], smin[1]), fminf(smin[2], smin[3]));
    float M = fmaxf(fmaxf(smax[0], smax[1]), fmaxf(smax[2], smax[3]));
    scratch[blockIdx.x]        = m;
    scratch[2048 + blockIdx.x] = M;
  }
}

__global__ __launch_bounds__(256) void k_vpfx4(const float* __restrict__ x,
                                               const float* __restrict__ scratch,
                                               float* __restrict__ P) {
  int bid = blockIdx.x;
  int b = bid / W, w = bid % W;
  int seg = threadIdx.x >> 4;
  int chg = threadIdx.x & 15;
  int wv  = threadIdx.x >> 6;

  float vmn = fminf(scratch[b*512 + threadIdx.x], scratch[b*512 + 256 + threadIdx.x]);
  float vmx = fmaxf(scratch[2048 + b*512 + threadIdx.x], scratch[2048 + b*512 + 256 + threadIdx.x]);
  __shared__ float smin[4], smax[4];
  float wmn = wave_reduce_min(vmn), wmx = wave_reduce_max(vmx);
  if ((threadIdx.x & 63) == 0) { smin[wv] = wmn; smax[wv] = wmx; }
  __syncthreads();
  float xmin = fminf(fminf(smin[0], smin[1]), fminf(smin[2], smin[3]));
  float xmax = fmaxf(fmaxf(smax[0], smax[1]), fmaxf(smax[2], smax[3]));
  float inv  = 1.0f / (xmax - xmin + 1e-6f);

  const size_t colbase = (size_t)b*HWC + (size_t)w*C;
  const float4* xp4 = (const float4*)(x + colbase);
  const int RS4 = WC / 4;
  const int r0 = seg * 14;

  float4 v4[14];
  #pragma unroll
  for (int j = 0; j < 14; ++j) v4[j] = xp4[(size_t)(r0 + j) * RS4 + chg];

  float4 s4 = v4[0];
  #pragma unroll
  for (int j = 1; j < 14; ++j) {
    s4.x += v4[j].x; s4.y += v4[j].y; s4.z += v4[j].z; s4.w += v4[j].w;
  }

  __shared__ float4 segsum[16][16];
  segsum[seg][chg] = s4;
  __syncthreads();

  float4 o4 = {0.f, 0.f, 0.f, 0.f};
  #pragma unroll
  for (int ss = 0; ss < 16; ++ss) {
    if (ss < seg) {
      float4 t = segsum[ss][chg];
      o4.x += t.x; o4.y += t.y; o4.z += t.z; o4.w += t.w;
    }
  }

  float4* Pp4 = (float4*)(P + colbase);
  float ax = o4.x, ay = o4.y, az = o4.z, aw = o4.w;
  #pragma unroll
  for (int j = 0; j < 14; ++j) {
    ax += v4[j].x; ay += v4[j].y; az += v4[j].z; aw += v4[j].w;
    float sub = (float)(r0 + j + 1) * xmin;
    float4 outv;
    outv.x = (ax - sub) * inv;
    outv.y = (ay - sub) * inv;
    outv.z = (az - sub) * inv;
    outv.w = (aw - sub) * inv;
    Pp4[(size_t)(r0 + j) * RS4 + chg] = outv;
  }
}

__global__ __launch_bounds__(128) void k_main(
    const float* __restrict__ P, const float* __restrict__ x,
    const float* __restrict__ ols, const float* __restrict__ anchors,
    const float* __restrict__ hwidths, const float* __restrict__ bn_gamma,
    const float* __restrict__ bn_beta, const float* __restrict__ bn_mean,
    const float* __restrict__ bn_var, float* __restrict__ out) {
  int xcd  = blockIdx.x & 7;
  int i    = blockIdx.x >> 3;
  int rg   = xcd * 112 + (i >> 2);
  int wave = threadIdx.x >> 6, c = threadIdx.x & 63;
  int chunk = (i & 3) * 2 + wave;
  int b = rg / H, h = rg % H;
  int w0 = chunk * 28;

  const float LN2 = 0.69314718055994530942f;
  float wg0 = ols[0], wg1 = ols[1], wg2 = ols[2], wg3 = ols[3];
  float l0 = LN2, l1 = 2.f*LN2, l2 = 3.f*LN2, l3 = 4.f*LN2;
  float wsum = wg0 + wg1 + wg2 + wg3;
  float lrbar = (wg0*l0 + wg1*l1 + wg2*l2 + wg3*l3) / wsum;
  float d0 = l0-lrbar, d1 = l1-lrbar, d2 = l2-lrbar, d3 = l3-lrbar;
  float den = wg0*d0*d0 + wg1*d1*d1 + wg2*d2*d2 + wg3*d3*d3;
  float c0 = wg0*d0/den, c1 = wg1*d1/den, c2 = wg2*d2/den, c3 = wg3*d3/den;

  float scl  = bn_gamma[c] * rsqrtf(bn_var[c] + 1e-3f);
  float bofs = bn_beta[c] - bn_mean[c] * scl;
  float anc[K], wd[K];
  #pragma unroll
  for (int k = 0; k < K; ++k) { anc[k] = anchors[c*K + k]; wd[k] = hwidths[c*K + k]; }

  const int hiA[4] = {1, 2, 4, 8};
  const int loA[4] = {0, 1, 3, 7};
  const float* pt[4]; const float* pb[4]; float fb[4];
  #pragma unroll
  for (int s = 0; s < 4; ++s) {
    int ht = h + hiA[s]; if (ht > H-1) ht = H-1;
    int hb = h - loA[s] - 1;
    int hbc = hb < 0 ? 0 : hb;
    pt[s] = P + (size_t)b*HWC + (size_t)ht*WC + c;
    pb[s] = P + (size_t)b*HWC + (size_t)hbc*WC + c;
    fb[s] = hb < 0 ? 0.f : 1.f;
  }

  const float* xrow = x   + (size_t)b*HWC + (size_t)h*WC + c;
  float*       orow = out + (size_t)b*HWC + (size_t)h*WC + c;

  float ring2[2]   = {0,0};
  float ring4[4]   = {0,0,0,0};
  float ring8[8]   = {0,0,0,0,0,0,0,0};
  float ring16[16] = {0,0,0,0,0,0,0,0,0,0,0,0,0,0,0,0};
  float T0 = 0.f, T1 = 0.f, T2 = 0.f, T3 = 0.f;
  float abuf[8] = {0,0,0,0,0,0,0,0};

  for (int t0 = 0; t0 < 48; t0 += 16) {
    #pragma unroll
    for (int u = 0; u < 16; ++u) {
      int t  = t0 + u;
      int wr = w0 - 7 + t;
      float m0 = 0.f, m1 = 0.f, m2 = 0.f, m3 = 0.f;
      if (wr >= 0 && wr < W) {
        int off = wr * C;
        m0 = pt[0][off] - fb[0]*pb[0][off];
        m1 = pt[1][off] - fb[1]*pb[1][off];
        m2 = pt[2][off] - fb[2]*pb[2][off];
        m3 = pt[3][off] - fb[3]*pb[3][off];
      }
      T0 += m0 - ring2[u&1];  ring2[u&1]  = m0;
      T1 += m1 - ring4[u&3];  ring4[u&3]  = m1;
      T2 += m2 - ring8[u&7];  ring8[u&7]  = m2;
      T3 += m3 - ring16[u];   ring16[u]   = m3;
      abuf[(u+7)&7] += c0 * __logf(fmaxf(T0, 0.f) + 1e-6f);
      abuf[(u+6)&7] += c1 * __logf(fmaxf(T1, 0.f) + 1e-6f);
      abuf[(u+4)&7] += c2 * __logf(fmaxf(T2, 0.f) + 1e-6f);
      abuf[u&7]     += c3 * __logf(fmaxf(T3, 0.f) + 1e-6f);
      int ig = w0 - 15 + t;
      if (t >= 15 && ig <= w0 + 27) {
        float alpha = abuf[u&7];
        float a = alpha * scl + bofs;
        float sc = 0.f;
        #pragma unroll
        for (int k = 0; k < K; ++k)
          sc += fmaxf(0.f, 1.f - wd[k]*fabsf(a - anc[k]));
        float sig = 1.f / (1.f + __expf(-sc));
        float xv = __builtin_nontemporal_load(&xrow[ig*C]);
        __builtin_nontemporal_store(xv + sig, &orow[ig*C]);
      }
      abuf[u&7] = 0.f;
    }
  }
}

// ================================ host ================================

extern "C" void kernel_launch(void* const* d_in, const int* in_sizes, int n_in,
                              void* d_out, int out_size, void* d_ws, size_t ws_size,
                              hipStream_t stream) {
  const float* x        = (const float*)d_in[0];
  const float* ols      = (const float*)d_in[1];
  const float* anchors  = (const float*)d_in[2];
  const float* hwidths  = (const float*)d_in[3];
  const float* bn_gamma = (const float*)d_in[4];
  const float* bn_beta  = (const float*)d_in[5];
  const float* bn_mean  = (const float*)d_in[6];
  const float* bn_var   = (const float*)d_in[7];
  float* out = (float*)d_out;
  float* P   = (float*)d_ws;                      // B*H*W*C floats = 51.4 MB
  const size_t PBYTES = (size_t)B * HWC * sizeof(float);

  if (ws_size >= PBYTES + 8192) {
    // fast path: wave-contiguous producer + 56-chunk deferred-norm consumer
    float* pmn = (float*)((char*)d_ws + PBYTES);  // 896 used, 1024 reserved
    float* pmx = pmn + 1024;
    hipLaunchKernelGGL(k_vpfx_wide, dim3(B*56),  dim3(1024), 0, stream, x, P, pmn, pmx);
    hipLaunchKernelGGL(k_main2,     dim3(B*H*2), dim3(128),  0, stream,
                       P, x, pmn, pmx, ols, anchors, hwidths,
                       bn_gamma, bn_beta, bn_mean, bn_var, out);
  } else {
    // fallback: verbatim R3 3-kernel pipeline (scratch in d_out)
    float* scratch = out;
    hipLaunchKernelGGL(k_minmax_part, dim3(2048),  dim3(256), 0, stream, x, scratch);
    hipLaunchKernelGGL(k_vpfx4,       dim3(B*W),   dim3(256), 0, stream, x, scratch, P);
    hipLaunchKernelGGL(k_main,        dim3(B*H*4), dim3(128), 0, stream,
                       P, x, ols, anchors, hwidths,
                       bn_gamma, bn_beta, bn_mean, bn_var, out);
  }
}

// Round 9
// 199.098 us; speedup vs baseline: 1.1318x; 1.0621x over previous
//
#include <hip/hip_runtime.h>
#include <math.h>

#define B 4
#define H 224
#define W 224
#define C 64
#define K 8
#define WC (W*C)        // 14336
#define HWC (H*W*C)     // 3211264

__device__ inline float wave_reduce_min(float v) {
  #pragma unroll
  for (int off = 32; off > 0; off >>= 1)
    v = fminf(v, __shfl_down(v, off, 64));
  return v;
}
__device__ inline float wave_reduce_max(float v) {
  #pragma unroll
  for (int off = 32; off > 0; off >>= 1)
    v = fmaxf(v, __shfl_down(v, off, 64));
  return v;
}

struct FalseT { static constexpr bool value = false; };
struct TrueT  { static constexpr bool value = true; };

// ================= FAST PATH =================

// ---- Kernel 0: per-block partial min/max per sample (verified R0/R3 body) ----
// Partials live in d_ws (no d_out race with the fused consumer).
__global__ __launch_bounds__(256) void k_minmax_part(const float* __restrict__ x,
                                                     float* __restrict__ scratch) {
  int s   = blockIdx.x >> 9;      // 512 blocks per sample
  int blk = blockIdx.x & 511;
  const float4* xs = (const float4*)(x + (size_t)s * HWC);
  const int n4 = HWC / 4;
  float vmin = INFINITY, vmax = -INFINITY;
  for (int i = blk*256 + threadIdx.x; i < n4; i += 512*256) {
    float4 v = xs[i];
    vmin = fminf(vmin, fminf(fminf(v.x, v.y), fminf(v.z, v.w)));
    vmax = fmaxf(vmax, fmaxf(fmaxf(v.x, v.y), fmaxf(v.z, v.w)));
  }
  __shared__ float smin[4], smax[4];
  float wmin = wave_reduce_min(vmin), wmax = wave_reduce_max(vmax);
  int wave = threadIdx.x >> 6, lane = threadIdx.x & 63;
  if (lane == 0) { smin[wave] = wmin; smax[wave] = wmax; }
  __syncthreads();
  if (threadIdx.x == 0) {
    float m = fminf(fminf(smin[0], smin[1]), fminf(smin[2], smin[3]));
    float M = fmaxf(fmaxf(smax[0], smax[1]), fmaxf(smax[2], smax[3]));
    scratch[blockIdx.x]        = m;
    scratch[2048 + blockIdx.x] = M;
  }
}

// ---- Kernel 1: FUSED everything (R9) -------------------------------------
// R8's k_main2 (56-chunk, deferred-norm, verbatim rings/abuf/epilogue) with the
// P reads replaced by direct 16-row vertical window sums from x:
//   m_s = sum over rows [h-loA[s], h+hiA[s]] (zero-padded) at column wr.
// Nested windows (s0 c s1 c s2 c s3) -> 16 loads + ~19 fma per step from 16
// block-uniform row pointers. The x value for the final add is v7 (row h)
// loaded 8 steps earlier -> xring[8]. Eliminates P (51MB write + 51MB read)
// and the producer kernel entirely.
__global__ __launch_bounds__(128) void k_fused(
    const float* __restrict__ x, const float* __restrict__ scratch,
    const float* __restrict__ ols, const float* __restrict__ anchors,
    const float* __restrict__ hwidths, const float* __restrict__ bn_gamma,
    const float* __restrict__ bn_beta, const float* __restrict__ bn_mean,
    const float* __restrict__ bn_var, float* __restrict__ out) {
  int xcd  = blockIdx.x & 7;
  int i    = blockIdx.x >> 3;        // [0,224)
  int rg   = xcd * 112 + (i >> 1);   // global row in [0,896)
  int wave = threadIdx.x >> 6, c = threadIdx.x & 63;
  int chunk = (i & 1) * 2 + wave;    // [0,4)
  int b = rg / H, h = rg % H;
  int w0 = chunk * 56;

  // --- finalize per-sample min/max from 512 partials (L2-hot, 4/thread) ---
  float vmn = fminf(fminf(scratch[b*512 + threadIdx.x],
                          scratch[b*512 + threadIdx.x + 128]),
                    fminf(scratch[b*512 + threadIdx.x + 256],
                          scratch[b*512 + threadIdx.x + 384]));
  float vmx = fmaxf(fmaxf(scratch[2048 + b*512 + threadIdx.x],
                          scratch[2048 + b*512 + threadIdx.x + 128]),
                    fmaxf(scratch[2048 + b*512 + threadIdx.x + 256],
                          scratch[2048 + b*512 + threadIdx.x + 384]));
  vmn = wave_reduce_min(vmn);
  vmx = wave_reduce_max(vmx);
  __shared__ float sred[4];
  if ((threadIdx.x & 63) == 0) { sred[wave*2] = vmn; sred[wave*2+1] = vmx; }
  __syncthreads();
  float xmin = fminf(sred[0], sred[2]);
  float xmax = fmaxf(sred[1], sred[3]);
  float rng  = xmax - xmin + 1e-6f;
  float epsp = 1e-6f * rng;          // eps lifted to the unnormalized domain

  const float LN2 = 0.69314718055994530942f;
  float wg0 = ols[0], wg1 = ols[1], wg2 = ols[2], wg3 = ols[3];
  float l0 = LN2, l1 = 2.f*LN2, l2 = 3.f*LN2, l3 = 4.f*LN2;
  float wsum = wg0 + wg1 + wg2 + wg3;
  float lrbar = (wg0*l0 + wg1*l1 + wg2*l2 + wg3*l3) / wsum;
  float d0 = l0-lrbar, d1 = l1-lrbar, d2 = l2-lrbar, d3 = l3-lrbar;
  float den = wg0*d0*d0 + wg1*d1*d1 + wg2*d2*d2 + wg3*d3*d3;
  float c0 = wg0*d0/den, c1 = wg1*d1/den, c2 = wg2*d2/den, c3 = wg3*d3/den;

  float scl  = bn_gamma[c] * rsqrtf(bn_var[c] + 1e-3f);
  float bofs = bn_beta[c] - bn_mean[c] * scl;
  float anc[K], wd[K];
  #pragma unroll
  for (int k = 0; k < K; ++k) { anc[k] = anchors[c*K + k]; wd[k] = hwidths[c*K + k]; }

  const int hiA[4] = {1, 2, 4, 8};
  const int loA[4] = {0, 1, 3, 7};
  const int rA[4]  = {2, 4, 8, 16};
  float Anh[4], Kin[4];
  #pragma unroll
  for (int s = 0; s < 4; ++s) {
    int ht = h + hiA[s]; if (ht > H-1) ht = H-1;
    int h0 = h - loA[s]; if (h0 < 0) h0 = 0;
    int nv = ht - h0 + 1;              // in-bounds rows of the vertical window
    Anh[s] = -(float)nv * xmin;        // per-column xmin correction factor
    Kin[s] = (float)rA[s] * Anh[s] + epsp;   // interior: nh == r, eps folded
  }

  // --- 16 row bases (block-uniform -> SGPRs; c folded into the lane offset) ---
  const float* rb[16]; float fr[16];
  const size_t sbase = (size_t)b * HWC;
  #pragma unroll
  for (int r16 = 0; r16 < 16; ++r16) {
    int r  = h - 7 + r16;
    int rc = r < 0 ? 0 : (r > H-1 ? H-1 : r);
    rb[r16] = x + sbase + (size_t)rc * WC;
    fr[r16] = (r >= 0 && r <= H-1) ? 1.f : 0.f;
  }

  float* orow = out + sbase + (size_t)h*WC + c;

  auto tloop = [&](auto EDGEC) {
    constexpr bool EDGE = decltype(EDGEC)::value;
    float ring2[2]   = {0,0};
    float ring4[4]   = {0,0,0,0};
    float ring8[8]   = {0,0,0,0,0,0,0,0};
    float ring16[16] = {0,0,0,0,0,0,0,0,0,0,0,0,0,0,0,0};
    float xring[8]   = {0,0,0,0,0,0,0,0};
    float T0 = 0.f, T1 = 0.f, T2 = 0.f, T3 = 0.f;
    float abuf[8] = {0,0,0,0,0,0,0,0};

    for (int t0 = 0; t0 < 80; t0 += 16) {      // 80 steps: 15 warmup + 56 out + pad
      #pragma unroll
      for (int u = 0; u < 16; ++u) {
        int t  = t0 + u;
        int wr = w0 - 7 + t;
        float m0, m1, m2, m3, xnew;
        if constexpr (EDGE) {
          m0 = m1 = m2 = m3 = 0.f; xnew = 0.f;
          if (wr >= 0 && wr < W) {
            int off = wr * C + c;
            float v00 = rb[0][off],  v01 = rb[1][off],  v02 = rb[2][off],  v03 = rb[3][off];
            float v04 = rb[4][off],  v05 = rb[5][off],  v06 = rb[6][off],  v07 = rb[7][off];
            float v08 = rb[8][off],  v09 = rb[9][off],  v10 = rb[10][off], v11 = rb[11][off];
            float v12 = rb[12][off], v13 = rb[13][off], v14 = rb[14][off], v15 = rb[15][off];
            m0 = fr[7]*v07 + fr[8]*v08;
            m1 = m0 + fr[6]*v06 + fr[9]*v09;
            m2 = m1 + fr[4]*v04 + fr[5]*v05 + fr[10]*v10 + fr[11]*v11;
            m3 = m2 + fr[0]*v00 + fr[1]*v01 + fr[2]*v02 + fr[3]*v03
                    + fr[12]*v12 + fr[13]*v13 + fr[14]*v14 + fr[15]*v15;
            xnew = v07;                      // row h is always valid (fr[7]==1)
          }
        } else {
          int off = wr * C + c;
          float v00 = rb[0][off],  v01 = rb[1][off],  v02 = rb[2][off],  v03 = rb[3][off];
          float v04 = rb[4][off],  v05 = rb[5][off],  v06 = rb[6][off],  v07 = rb[7][off];
          float v08 = rb[8][off],  v09 = rb[9][off],  v10 = rb[10][off], v11 = rb[11][off];
          float v12 = rb[12][off], v13 = rb[13][off], v14 = rb[14][off], v15 = rb[15][off];
          m0 = fr[7]*v07 + fr[8]*v08;
          m1 = m0 + fr[6]*v06 + fr[9]*v09;
          m2 = m1 + fr[4]*v04 + fr[5]*v05 + fr[10]*v10 + fr[11]*v11;
          m3 = m2 + fr[0]*v00 + fr[1]*v01 + fr[2]*v02 + fr[3]*v03
                  + fr[12]*v12 + fr[13]*v13 + fr[14]*v14 + fr[15]*v15;
          xnew = v07;
        }

        // x[h][ig] for the output 8 steps from now sits in xring; (t-8)&7 == t&7,
        // so read the old slot BEFORE overwriting it this step.
        float xv_old = xring[u&7];
        xring[u&7] = xnew;

        T0 += m0 - ring2[u&1];  ring2[u&1]  = m0;
        T1 += m1 - ring4[u&3];  ring4[u&3]  = m1;
        T2 += m2 - ring8[u&7];  ring8[u&7]  = m2;
        T3 += m3 - ring16[u];   ring16[u]   = m3;

        float a0, a1, a2, a3;
        if constexpr (EDGE) {
          float nh0 = (float)(min(wr, W-1) - max(wr-1,  0) + 1);
          float nh1 = (float)(min(wr, W-1) - max(wr-3,  0) + 1);
          float nh2 = (float)(min(wr, W-1) - max(wr-7,  0) + 1);
          float nh3 = (float)(min(wr, W-1) - max(wr-15, 0) + 1);
          a0 = fmaxf(fmaf(Anh[0], nh0, T0) + epsp, epsp);
          a1 = fmaxf(fmaf(Anh[1], nh1, T1) + epsp, epsp);
          a2 = fmaxf(fmaf(Anh[2], nh2, T2) + epsp, epsp);
          a3 = fmaxf(fmaf(Anh[3], nh3, T3) + epsp, epsp);
        } else {
          a0 = fmaxf(T0 + Kin[0], epsp);
          a1 = fmaxf(T1 + Kin[1], epsp);
          a2 = fmaxf(T2 + Kin[2], epsp);
          a3 = fmaxf(T3 + Kin[3], epsp);
        }
        abuf[(u+7)&7] += c0 * __logf(a0);
        abuf[(u+6)&7] += c1 * __logf(a1);
        abuf[(u+4)&7] += c2 * __logf(a2);
        abuf[u&7]     += c3 * __logf(a3);

        int ig = w0 - 15 + t;
        if (t >= 15 && t <= 70) {              // ig in [w0, w0+55]
          float alpha = abuf[u&7];
          float a = alpha * scl + bofs;
          float sc = 0.f;
          #pragma unroll
          for (int k = 0; k < K; ++k)
            sc += fmaxf(0.f, 1.f - wd[k]*fabsf(a - anc[k]));
          float sig = 1.f / (1.f + __expf(-sc));
          __builtin_nontemporal_store(xv_old + sig, &orow[ig*C]);
        }
        abuf[u&7] = 0.f;
      }
    }
  };
  // interior iff full 16-wide windows for every contributing step (w0>=22)
  // and unchecked loads in-bounds for all t<80 (w0+72 <= 223 -> w0 <= 151)
  if (w0 >= 22 && w0 <= 151) tloop(FalseT{}); else tloop(TrueT{});
}

// ================= FALLBACK PATH (verbatim R3 pipeline) =================

__global__ __launch_bounds__(256) void k_vpfx4(const float* __restrict__ x,
                                               const float* __restrict__ scratch,
                                               float* __restrict__ P) {
  int bid = blockIdx.x;
  int b = bid / W, w = bid % W;
  int seg = threadIdx.x >> 4;
  int chg = threadIdx.x & 15;
  int wv  = threadIdx.x >> 6;

  float vmn = fminf(scratch[b*512 + threadIdx.x], scratch[b*512 + 256 + threadIdx.x]);
  float vmx = fmaxf(scratch[2048 + b*512 + threadIdx.x], scratch[2048 + b*512 + 256 + threadIdx.x]);
  __shared__ float smin[4], smax[4];
  float wmn = wave_reduce_min(vmn), wmx = wave_reduce_max(vmx);
  if ((threadIdx.x & 63) == 0) { smin[wv] = wmn; smax[wv] = wmx; }
  __syncthreads();
  float xmin = fminf(fminf(smin[0], smin[1]), fminf(smin[2], smin[3]));
  float xmax = fmaxf(fmaxf(smax[0], smax[1]), fmaxf(smax[2], smax[3]));
  float inv  = 1.0f / (xmax - xmin + 1e-6f);

  const size_t colbase = (size_t)b*HWC + (size_t)w*C;
  const float4* xp4 = (const float4*)(x + colbase);
  const int RS4 = WC / 4;
  const int r0 = seg * 14;

  float4 v4[14];
  #pragma unroll
  for (int j = 0; j < 14; ++j) v4[j] = xp4[(size_t)(r0 + j) * RS4 + chg];

  float4 s4 = v4[0];
  #pragma unroll
  for (int j = 1; j < 14; ++j) {
    s4.x += v4[j].x; s4.y += v4[j].y; s4.z += v4[j].z; s4.w += v4[j].w;
  }

  __shared__ float4 segsum[16][16];
  segsum[seg][chg] = s4;
  __syncthreads();

  float4 o4 = {0.f, 0.f, 0.f, 0.f};
  #pragma unroll
  for (int ss = 0; ss < 16; ++ss) {
    if (ss < seg) {
      float4 t = segsum[ss][chg];
      o4.x += t.x; o4.y += t.y; o4.z += t.z; o4.w += t.w;
    }
  }

  float4* Pp4 = (float4*)(P + colbase);
  float ax = o4.x, ay = o4.y, az = o4.z, aw = o4.w;
  #pragma unroll
  for (int j = 0; j < 14; ++j) {
    ax += v4[j].x; ay += v4[j].y; az += v4[j].z; aw += v4[j].w;
    float sub = (float)(r0 + j + 1) * xmin;
    float4 outv;
    outv.x = (ax - sub) * inv;
    outv.y = (ay - sub) * inv;
    outv.z = (az - sub) * inv;
    outv.w = (aw - sub) * inv;
    Pp4[(size_t)(r0 + j) * RS4 + chg] = outv;
  }
}

__global__ __launch_bounds__(128) void k_main(
    const float* __restrict__ P, const float* __restrict__ x,
    const float* __restrict__ ols, const float* __restrict__ anchors,
    const float* __restrict__ hwidths, const float* __restrict__ bn_gamma,
    const float* __restrict__ bn_beta, const float* __restrict__ bn_mean,
    const float* __restrict__ bn_var, float* __restrict__ out) {
  int xcd  = blockIdx.x & 7;
  int i    = blockIdx.x >> 3;
  int rg   = xcd * 112 + (i >> 2);
  int wave = threadIdx.x >> 6, c = threadIdx.x & 63;
  int chunk = (i & 3) * 2 + wave;
  int b = rg / H, h = rg % H;
  int w0 = chunk * 28;

  const float LN2 = 0.69314718055994530942f;
  float wg0 = ols[0], wg1 = ols[1], wg2 = ols[2], wg3 = ols[3];
  float l0 = LN2, l1 = 2.f*LN2, l2 = 3.f*LN2, l3 = 4.f*LN2;
  float wsum = wg0 + wg1 + wg2 + wg3;
  float lrbar = (wg0*l0 + wg1*l1 + wg2*l2 + wg3*l3) / wsum;
  float d0 = l0-lrbar, d1 = l1-lrbar, d2 = l2-lrbar, d3 = l3-lrbar;
  float den = wg0*d0*d0 + wg1*d1*d1 + wg2*d2*d2 + wg3*d3*d3;
  float c0 = wg0*d0/den, c1 = wg1*d1/den, c2 = wg2*d2/den, c3 = wg3*d3/den;

  float scl  = bn_gamma[c] * rsqrtf(bn_var[c] + 1e-3f);
  float bofs = bn_beta[c] - bn_mean[c] * scl;
  float anc[K], wd[K];
  #pragma unroll
  for (int k = 0; k < K; ++k) { anc[k] = anchors[c*K + k]; wd[k] = hwidths[c*K + k]; }

  const int hiA[4] = {1, 2, 4, 8};
  const int loA[4] = {0, 1, 3, 7};
  const float* pt[4]; const float* pb[4]; float fb[4];
  #pragma unroll
  for (int s = 0; s < 4; ++s) {
    int ht = h + hiA[s]; if (ht > H-1) ht = H-1;
    int hb = h - loA[s] - 1;
    int hbc = hb < 0 ? 0 : hb;
    pt[s] = P + (size_t)b*HWC + (size_t)ht*WC + c;
    pb[s] = P + (size_t)b*HWC + (size_t)hbc*WC + c;
    fb[s] = hb < 0 ? 0.f : 1.f;
  }

  const float* xrow = x   + (size_t)b*HWC + (size_t)h*WC + c;
  float*       orow = out + (size_t)b*HWC + (size_t)h*WC + c;

  float ring2[2]   = {0,0};
  float ring4[4]   = {0,0,0,0};
  float ring8[8]   = {0,0,0,0,0,0,0,0};
  float ring16[16] = {0,0,0,0,0,0,0,0,0,0,0,0,0,0,0,0};
  float T0 = 0.f, T1 = 0.f, T2 = 0.f, T3 = 0.f;
  float abuf[8] = {0,0,0,0,0,0,0,0};

  for (int t0 = 0; t0 < 48; t0 += 16) {
    #pragma unroll
    for (int u = 0; u < 16; ++u) {
      int t  = t0 + u;
      int wr = w0 - 7 + t;
      float m0 = 0.f, m1 = 0.f, m2 = 0.f, m3 = 0.f;
      if (wr >= 0 && wr < W) {
        int off = wr * C;
        m0 = pt[0][off] - fb[0]*pb[0][off];
        m1 = pt[1][off] - fb[1]*pb[1][off];
        m2 = pt[2][off] - fb[2]*pb[2][off];
        m3 = pt[3][off] - fb[3]*pb[3][off];
      }
      T0 += m0 - ring2[u&1];  ring2[u&1]  = m0;
      T1 += m1 - ring4[u&3];  ring4[u&3]  = m1;
      T2 += m2 - ring8[u&7];  ring8[u&7]  = m2;
      T3 += m3 - ring16[u];   ring16[u]   = m3;
      abuf[(u+7)&7] += c0 * __logf(fmaxf(T0, 0.f) + 1e-6f);
      abuf[(u+6)&7] += c1 * __logf(fmaxf(T1, 0.f) + 1e-6f);
      abuf[(u+4)&7] += c2 * __logf(fmaxf(T2, 0.f) + 1e-6f);
      abuf[u&7]     += c3 * __logf(fmaxf(T3, 0.f) + 1e-6f);
      int ig = w0 - 15 + t;
      if (t >= 15 && ig <= w0 + 27) {
        float alpha = abuf[u&7];
        float a = alpha * scl + bofs;
        float sc = 0.f;
        #pragma unroll
        for (int k = 0; k < K; ++k)
          sc += fmaxf(0.f, 1.f - wd[k]*fabsf(a - anc[k]));
        float sig = 1.f / (1.f + __expf(-sc));
        float xv = __builtin_nontemporal_load(&xrow[ig*C]);
        __builtin_nontemporal_store(xv + sig, &orow[ig*C]);
      }
      abuf[u&7] = 0.f;
    }
  }
}

// ================================ host ================================

extern "C" void kernel_launch(void* const* d_in, const int* in_sizes, int n_in,
                              void* d_out, int out_size, void* d_ws, size_t ws_size,
                              hipStream_t stream) {
  const float* x        = (const float*)d_in[0];
  const float* ols      = (const float*)d_in[1];
  const float* anchors  = (const float*)d_in[2];
  const float* hwidths  = (const float*)d_in[3];
  const float* bn_gamma = (const float*)d_in[4];
  const float* bn_beta  = (const float*)d_in[5];
  const float* bn_mean  = (const float*)d_in[6];
  const float* bn_var   = (const float*)d_in[7];
  float* out = (float*)d_out;

  if (ws_size >= 16384) {
    // fast path: min/max partials in ws (16 KB), then the fused kernel.
    // No P buffer at all: vertical sums computed directly from x (L2-resident
    // 16-row windows), x re-read for the final add folded into xring.
    float* scratch = (float*)d_ws;   // [0..2047] mins, [2048..4095] maxs
    hipLaunchKernelGGL(k_minmax_part, dim3(2048),  dim3(256), 0, stream, x, scratch);
    hipLaunchKernelGGL(k_fused,       dim3(B*H*2), dim3(128), 0, stream,
                       x, scratch, ols, anchors, hwidths,
                       bn_gamma, bn_beta, bn_mean, bn_var, out);
  } else {
    // fallback: verbatim R3 3-kernel pipeline (scratch in d_out, P in ws)
    float* P = (float*)d_ws;
    float* scratch = out;
    hipLaunchKernelGGL(k_minmax_part, dim3(2048),  dim3(256), 0, stream, x, scratch);
    hipLaunchKernelGGL(k_vpfx4,       dim3(B*W),   dim3(256), 0, stream, x, scratch, P);
    hipLaunchKernelGGL(k_main,        dim3(B*H*4), dim3(128), 0, stream,
                       P, x, ols, anchors, hwidths,
                       bn_gamma, bn_beta, bn_mean, bn_var, out);
  }
}

// Round 10
// 190.481 us; speedup vs baseline: 1.1830x; 1.0452x over previous
//
#include <hip/hip_runtime.h>
#include <math.h>

#define B 4
#define H 224
#define W 224
#define C 64
#define K 8
#define WC (W*C)        // 14336
#define HWC (H*W*C)     // 3211264

__device__ inline float wave_reduce_min(float v) {
  #pragma unroll
  for (int off = 32; off > 0; off >>= 1)
    v = fminf(v, __shfl_down(v, off, 64));
  return v;
}
__device__ inline float wave_reduce_max(float v) {
  #pragma unroll
  for (int off = 32; off > 0; off >>= 1)
    v = fmaxf(v, __shfl_down(v, off, 64));
  return v;
}

// ================= FAST PATH =================

// ---- Kernel 0: per-block partial min/max per sample (verified R0/R3 body) ----
// Also pre-warms x into L3 for k_fused2 (R9: FETCH 52->36 MB).
__global__ __launch_bounds__(256) void k_minmax_part(const float* __restrict__ x,
                                                     float* __restrict__ scratch) {
  int s   = blockIdx.x >> 9;      // 512 blocks per sample
  int blk = blockIdx.x & 511;
  const float4* xs = (const float4*)(x + (size_t)s * HWC);
  const int n4 = HWC / 4;
  float vmin = INFINITY, vmax = -INFINITY;
  for (int i = blk*256 + threadIdx.x; i < n4; i += 512*256) {
    float4 v = xs[i];
    vmin = fminf(vmin, fminf(fminf(v.x, v.y), fminf(v.z, v.w)));
    vmax = fmaxf(vmax, fmaxf(fmaxf(v.x, v.y), fmaxf(v.z, v.w)));
  }
  __shared__ float smin[4], smax[4];
  float wmin = wave_reduce_min(vmin), wmax = wave_reduce_max(vmax);
  int wave = threadIdx.x >> 6, lane = threadIdx.x & 63;
  if (lane == 0) { smin[wave] = wmin; smax[wave] = wmax; }
  __syncthreads();
  if (threadIdx.x == 0) {
    float m = fminf(fminf(smin[0], smin[1]), fminf(smin[2], smin[3]));
    float M = fmaxf(fmaxf(smax[0], smax[1]), fmaxf(smax[2], smax[3]));
    scratch[blockIdx.x]        = m;
    scratch[2048 + blockIdx.x] = M;
  }
}

// ---- Kernel 1: FUSED, 2-chunk-ILP version (R10) ---------------------------
// R9's k_fused with: (a) each wave handles TWO 56-chunks simultaneously
// (one edge + one interior -> single code path, 32 loads/step in flight),
// (b) loop shortened to exactly 71 steps (4x16 + 7-step epilogue; no 9-step
// tail waste). Per-output arithmetic and order identical to R9.
// wave0: E=w0 0,  I=w0 56;  wave1: E=w0 168, I=w0 112.
__global__ __launch_bounds__(128) void k_fused2(
    const float* __restrict__ x, const float* __restrict__ scratch,
    const float* __restrict__ ols, const float* __restrict__ anchors,
    const float* __restrict__ hwidths, const float* __restrict__ bn_gamma,
    const float* __restrict__ bn_beta, const float* __restrict__ bn_mean,
    const float* __restrict__ bn_var, float* __restrict__ out) {
  int xcd  = blockIdx.x & 7;
  int i    = blockIdx.x >> 3;        // [0,112)
  int rg   = xcd * 112 + i;          // global row in [0,896)
  int wave = threadIdx.x >> 6, c = threadIdx.x & 63;
  int b = rg / H, h = rg % H;
  const int wE0 = wave ? 168 : 0;    // edge chunk base
  const int wI0 = wave ? 112 : 56;   // interior chunk base

  // --- finalize per-sample min/max from 512 partials (L2-hot, 4/thread) ---
  float vmn = fminf(fminf(scratch[b*512 + threadIdx.x],
                          scratch[b*512 + threadIdx.x + 128]),
                    fminf(scratch[b*512 + threadIdx.x + 256],
                          scratch[b*512 + threadIdx.x + 384]));
  float vmx = fmaxf(fmaxf(scratch[2048 + b*512 + threadIdx.x],
                          scratch[2048 + b*512 + threadIdx.x + 128]),
                    fmaxf(scratch[2048 + b*512 + threadIdx.x + 256],
                          scratch[2048 + b*512 + threadIdx.x + 384]));
  vmn = wave_reduce_min(vmn);
  vmx = wave_reduce_max(vmx);
  __shared__ float sred[4];
  if ((threadIdx.x & 63) == 0) { sred[wave*2] = vmn; sred[wave*2+1] = vmx; }
  __syncthreads();
  float xmin = fminf(sred[0], sred[2]);
  float xmax = fmaxf(sred[1], sred[3]);
  float rng  = xmax - xmin + 1e-6f;
  float epsp = 1e-6f * rng;          // eps lifted to the unnormalized domain

  const float LN2 = 0.69314718055994530942f;
  float wg0 = ols[0], wg1 = ols[1], wg2 = ols[2], wg3 = ols[3];
  float l0 = LN2, l1 = 2.f*LN2, l2 = 3.f*LN2, l3 = 4.f*LN2;
  float wsum = wg0 + wg1 + wg2 + wg3;
  float lrbar = (wg0*l0 + wg1*l1 + wg2*l2 + wg3*l3) / wsum;
  float d0 = l0-lrbar, d1 = l1-lrbar, d2 = l2-lrbar, d3 = l3-lrbar;
  float den = wg0*d0*d0 + wg1*d1*d1 + wg2*d2*d2 + wg3*d3*d3;
  float c0 = wg0*d0/den, c1 = wg1*d1/den, c2 = wg2*d2/den, c3 = wg3*d3/den;

  float scl  = bn_gamma[c] * rsqrtf(bn_var[c] + 1e-3f);
  float bofs = bn_beta[c] - bn_mean[c] * scl;
  float anc[K], wd[K];
  #pragma unroll
  for (int k = 0; k < K; ++k) { anc[k] = anchors[c*K + k]; wd[k] = hwidths[c*K + k]; }

  const int hiA[4] = {1, 2, 4, 8};
  const int loA[4] = {0, 1, 3, 7};
  const int rA[4]  = {2, 4, 8, 16};
  float Anh[4], Kin[4];
  #pragma unroll
  for (int s = 0; s < 4; ++s) {
    int ht = h + hiA[s]; if (ht > H-1) ht = H-1;
    int h0 = h - loA[s]; if (h0 < 0) h0 = 0;
    int nv = ht - h0 + 1;
    Anh[s] = -(float)nv * xmin;
    Kin[s] = (float)rA[s] * Anh[s] + epsp;
  }

  // --- 16 row bases (block-uniform -> scalar regs), shared by both chunks ---
  const float* rb[16]; float fr[16];
  const size_t sbase = (size_t)b * HWC;
  #pragma unroll
  for (int r16 = 0; r16 < 16; ++r16) {
    int r  = h - 7 + r16;
    int rc = r < 0 ? 0 : (r > H-1 ? H-1 : r);
    rb[r16] = x + sbase + (size_t)rc * WC;
    fr[r16] = (r >= 0 && r <= H-1) ? 1.f : 0.f;
  }

  float* orow = out + sbase + (size_t)h*WC + c;

  float rE2[2]={0,0}, rE4[4]={0,0,0,0}, rE8[8]={0,0,0,0,0,0,0,0};
  float rE16[16]={0,0,0,0,0,0,0,0,0,0,0,0,0,0,0,0};
  float rI2[2]={0,0}, rI4[4]={0,0,0,0}, rI8[8]={0,0,0,0,0,0,0,0};
  float rI16[16]={0,0,0,0,0,0,0,0,0,0,0,0,0,0,0,0};
  float xrE[8]={0,0,0,0,0,0,0,0}, xrI[8]={0,0,0,0,0,0,0,0};
  float TE0=0.f,TE1=0.f,TE2=0.f,TE3=0.f, TI0=0.f,TI1=0.f,TI2=0.f,TI3=0.f;
  float abE[8]={0,0,0,0,0,0,0,0}, abI[8]={0,0,0,0,0,0,0,0};

  // One step: E chunk (bounds-checked, nh math) + I chunk (unchecked, Kin).
  // u_ must be compile-time after unroll; valid because t0 is a multiple of 16
  // (and the epilogue's t0=64 is 0 mod 16), so t&15==u_, t&7==u_&7.
#define FSTEP(u_, t_) do {                                                    \
    int t = (t_);                                                             \
    /* ---- E chunk loads ---- */                                             \
    int wrE = wE0 - 7 + t;                                                    \
    float mE0, mE1, mE2, mE3, xEnew;                                          \
    mE0 = mE1 = mE2 = mE3 = 0.f; xEnew = 0.f;                                 \
    if (wrE >= 0 && wrE < W) {                                                \
      int off = wrE * C + c;                                                  \
      float v00=rb[0][off],  v01=rb[1][off],  v02=rb[2][off],  v03=rb[3][off];\
      float v04=rb[4][off],  v05=rb[5][off],  v06=rb[6][off],  v07=rb[7][off];\
      float v08=rb[8][off],  v09=rb[9][off],  v10=rb[10][off], v11=rb[11][off];\
      float v12=rb[12][off], v13=rb[13][off], v14=rb[14][off], v15=rb[15][off];\
      mE0 = fr[7]*v07 + fr[8]*v08;                                            \
      mE1 = mE0 + fr[6]*v06 + fr[9]*v09;                                      \
      mE2 = mE1 + fr[4]*v04 + fr[5]*v05 + fr[10]*v10 + fr[11]*v11;            \
      mE3 = mE2 + fr[0]*v00 + fr[1]*v01 + fr[2]*v02 + fr[3]*v03               \
                + fr[12]*v12 + fr[13]*v13 + fr[14]*v14 + fr[15]*v15;          \
      xEnew = v07;                                                            \
    }                                                                         \
    /* ---- I chunk loads (always in-bounds) ---- */                          \
    int wrI = wI0 - 7 + t;                                                    \
    int offI = wrI * C + c;                                                   \
    float w00=rb[0][offI],  w01=rb[1][offI],  w02=rb[2][offI],  w03=rb[3][offI];\
    float w04=rb[4][offI],  w05=rb[5][offI],  w06=rb[6][offI],  w07=rb[7][offI];\
    float w08=rb[8][offI],  w09=rb[9][offI],  w10=rb[10][offI], w11=rb[11][offI];\
    float w12=rb[12][offI], w13=rb[13][offI], w14=rb[14][offI], w15=rb[15][offI];\
    float mI0 = fr[7]*w07 + fr[8]*w08;                                        \
    float mI1 = mI0 + fr[6]*w06 + fr[9]*w09;                                  \
    float mI2 = mI1 + fr[4]*w04 + fr[5]*w05 + fr[10]*w10 + fr[11]*w11;        \
    float mI3 = mI2 + fr[0]*w00 + fr[1]*w01 + fr[2]*w02 + fr[3]*w03           \
              + fr[12]*w12 + fr[13]*w13 + fr[14]*w14 + fr[15]*w15;            \
    float xInew = w07;                                                        \
    float xEold = xrE[(u_)&7]; xrE[(u_)&7] = xEnew;                           \
    float xIold = xrI[(u_)&7]; xrI[(u_)&7] = xInew;                           \
    TE0 += mE0 - rE2[(u_)&1];   rE2[(u_)&1]   = mE0;                          \
    TE1 += mE1 - rE4[(u_)&3];   rE4[(u_)&3]   = mE1;                          \
    TE2 += mE2 - rE8[(u_)&7];   rE8[(u_)&7]   = mE2;                          \
    TE3 += mE3 - rE16[(u_)&15]; rE16[(u_)&15] = mE3;                          \
    TI0 += mI0 - rI2[(u_)&1];   rI2[(u_)&1]   = mI0;                          \
    TI1 += mI1 - rI4[(u_)&3];   rI4[(u_)&3]   = mI1;                          \
    TI2 += mI2 - rI8[(u_)&7];   rI8[(u_)&7]   = mI2;                          \
    TI3 += mI3 - rI16[(u_)&15]; rI16[(u_)&15] = mI3;                          \
    /* a values: E uses per-step nh (handles both left/right edges),  */      \
    /* I uses the folded interior constant Kin. Verified R8 semantics. */     \
    float nh0 = (float)(min(wrE, W-1) - max(wrE-1,  0) + 1);                  \
    float nh1 = (float)(min(wrE, W-1) - max(wrE-3,  0) + 1);                  \
    float nh2 = (float)(min(wrE, W-1) - max(wrE-7,  0) + 1);                  \
    float nh3 = (float)(min(wrE, W-1) - max(wrE-15, 0) + 1);                  \
    float aE0 = fmaxf(fmaf(Anh[0], nh0, TE0) + epsp, epsp);                   \
    float aE1 = fmaxf(fmaf(Anh[1], nh1, TE1) + epsp, epsp);                   \
    float aE2 = fmaxf(fmaf(Anh[2], nh2, TE2) + epsp, epsp);                   \
    float aE3 = fmaxf(fmaf(Anh[3], nh3, TE3) + epsp, epsp);                   \
    float aI0 = fmaxf(TI0 + Kin[0], epsp);                                    \
    float aI1 = fmaxf(TI1 + Kin[1], epsp);                                    \
    float aI2 = fmaxf(TI2 + Kin[2], epsp);                                    \
    float aI3 = fmaxf(TI3 + Kin[3], epsp);                                    \
    abE[((u_)+7)&7] += c0 * __logf(aE0);                                      \
    abE[((u_)+6)&7] += c1 * __logf(aE1);                                      \
    abE[((u_)+4)&7] += c2 * __logf(aE2);                                      \
    abE[(u_)&7]     += c3 * __logf(aE3);                                      \
    abI[((u_)+7)&7] += c0 * __logf(aI0);                                      \
    abI[((u_)+6)&7] += c1 * __logf(aI1);                                      \
    abI[((u_)+4)&7] += c2 * __logf(aI2);                                      \
    abI[(u_)&7]     += c3 * __logf(aI3);                                      \
    if (t >= 15) {                                                            \
      int igE = wE0 - 15 + t;                                                 \
      float aa = abE[(u_)&7] * scl + bofs;                                    \
      float sc = 0.f;                                                         \
      _Pragma("unroll")                                                       \
      for (int k = 0; k < K; ++k)                                             \
        sc += fmaxf(0.f, 1.f - wd[k]*fabsf(aa - anc[k]));                     \
      float sig = 1.f / (1.f + __expf(-sc));                                  \
      __builtin_nontemporal_store(xEold + sig, &orow[igE*C]);                 \
      int igI = wI0 - 15 + t;                                                 \
      float ab = abI[(u_)&7] * scl + bofs;                                    \
      float sc2 = 0.f;                                                        \
      _Pragma("unroll")                                                       \
      for (int k = 0; k < K; ++k)                                             \
        sc2 += fmaxf(0.f, 1.f - wd[k]*fabsf(ab - anc[k]));                    \
      float sig2 = 1.f / (1.f + __expf(-sc2));                                \
      __builtin_nontemporal_store(xIold + sig2, &orow[igI*C]);                \
    }                                                                         \
    abE[(u_)&7] = 0.f; abI[(u_)&7] = 0.f;                                     \
  } while (0)

  // 4 full 16-step blocks (t = 0..63) + 7-step epilogue (t = 64..70).
  // Exactly 71 steps: 15 warmup + 56 outputs, zero tail waste.
  for (int t0 = 0; t0 < 64; t0 += 16) {
    #pragma unroll
    for (int u = 0; u < 16; ++u) FSTEP(u, t0 + u);
  }
  #pragma unroll
  for (int u = 0; u < 7; ++u) FSTEP(u, 64 + u);
#undef FSTEP
}

// ================= FALLBACK PATH (verbatim R3 pipeline) =================

__global__ __launch_bounds__(256) void k_vpfx4(const float* __restrict__ x,
                                               const float* __restrict__ scratch,
                                               float* __restrict__ P) {
  int bid = blockIdx.x;
  int b = bid / W, w = bid % W;
  int seg = threadIdx.x >> 4;
  int chg = threadIdx.x & 15;
  int wv  = threadIdx.x >> 6;

  float vmn = fminf(scratch[b*512 + threadIdx.x], scratch[b*512 + 256 + threadIdx.x]);
  float vmx = fmaxf(scratch[2048 + b*512 + threadIdx.x], scratch[2048 + b*512 + 256 + threadIdx.x]);
  __shared__ float smin[4], smax[4];
  float wmn = wave_reduce_min(vmn), wmx = wave_reduce_max(vmx);
  if ((threadIdx.x & 63) == 0) { smin[wv] = wmn; smax[wv] = wmx; }
  __syncthreads();
  float xmin = fminf(fminf(smin[0], smin[1]), fminf(smin[2], smin[3]));
  float xmax = fmaxf(fmaxf(smax[0], smax[1]), fmaxf(smax[2], smax[3]));
  float inv  = 1.0f / (xmax - xmin + 1e-6f);

  const size_t colbase = (size_t)b*HWC + (size_t)w*C;
  const float4* xp4 = (const float4*)(x + colbase);
  const int RS4 = WC / 4;
  const int r0 = seg * 14;

  float4 v4[14];
  #pragma unroll
  for (int j = 0; j < 14; ++j) v4[j] = xp4[(size_t)(r0 + j) * RS4 + chg];

  float4 s4 = v4[0];
  #pragma unroll
  for (int j = 1; j < 14; ++j) {
    s4.x += v4[j].x; s4.y += v4[j].y; s4.z += v4[j].z; s4.w += v4[j].w;
  }

  __shared__ float4 segsum[16][16];
  segsum[seg][chg] = s4;
  __syncthreads();

  float4 o4 = {0.f, 0.f, 0.f, 0.f};
  #pragma unroll
  for (int ss = 0; ss < 16; ++ss) {
    if (ss < seg) {
      float4 t = segsum[ss][chg];
      o4.x += t.x; o4.y += t.y; o4.z += t.z; o4.w += t.w;
    }
  }

  float4* Pp4 = (float4*)(P + colbase);
  float ax = o4.x, ay = o4.y, az = o4.z, aw = o4.w;
  #pragma unroll
  for (int j = 0; j < 14; ++j) {
    ax += v4[j].x; ay += v4[j].y; az += v4[j].z; aw += v4[j].w;
    float sub = (float)(r0 + j + 1) * xmin;
    float4 outv;
    outv.x = (ax - sub) * inv;
    outv.y = (ay - sub) * inv;
    outv.z = (az - sub) * inv;
    outv.w = (aw - sub) * inv;
    Pp4[(size_t)(r0 + j) * RS4 + chg] = outv;
  }
}

__global__ __launch_bounds__(128) void k_main(
    const float* __restrict__ P, const float* __restrict__ x,
    const float* __restrict__ ols, const float* __restrict__ anchors,
    const float* __restrict__ hwidths, const float* __restrict__ bn_gamma,
    const float* __restrict__ bn_beta, const float* __restrict__ bn_mean,
    const float* __restrict__ bn_var, float* __restrict__ out) {
  int xcd  = blockIdx.x & 7;
  int i    = blockIdx.x >> 3;
  int rg   = xcd * 112 + (i >> 2);
  int wave = threadIdx.x >> 6, c = threadIdx.x & 63;
  int chunk = (i & 3) * 2 + wave;
  int b = rg / H, h = rg % H;
  int w0 = chunk * 28;

  const float LN2 = 0.69314718055994530942f;
  float wg0 = ols[0], wg1 = ols[1], wg2 = ols[2], wg3 = ols[3];
  float l0 = LN2, l1 = 2.f*LN2, l2 = 3.f*LN2, l3 = 4.f*LN2;
  float wsum = wg0 + wg1 + wg2 + wg3;
  float lrbar = (wg0*l0 + wg1*l1 + wg2*l2 + wg3*l3) / wsum;
  float d0 = l0-lrbar, d1 = l1-lrbar, d2 = l2-lrbar, d3 = l3-lrbar;
  float den = wg0*d0*d0 + wg1*d1*d1 + wg2*d2*d2 + wg3*d3*d3;
  float c0 = wg0*d0/den, c1 = wg1*d1/den, c2 = wg2*d2/den, c3 = wg3*d3/den;

  float scl  = bn_gamma[c] * rsqrtf(bn_var[c] + 1e-3f);
  float bofs = bn_beta[c] - bn_mean[c] * scl;
  float anc[K], wd[K];
  #pragma unroll
  for (int k = 0; k < K; ++k) { anc[k] = anchors[c*K + k]; wd[k] = hwidths[c*K + k]; }

  const int hiA[4] = {1, 2, 4, 8};
  const int loA[4] = {0, 1, 3, 7};
  const float* pt[4]; const float* pb[4]; float fb[4];
  #pragma unroll
  for (int s = 0; s < 4; ++s) {
    int ht = h + hiA[s]; if (ht > H-1) ht = H-1;
    int hb = h - loA[s] - 1;
    int hbc = hb < 0 ? 0 : hb;
    pt[s] = P + (size_t)b*HWC + (size_t)ht*WC + c;
    pb[s] = P + (size_t)b*HWC + (size_t)hbc*WC + c;
    fb[s] = hb < 0 ? 0.f : 1.f;
  }

  const float* xrow = x   + (size_t)b*HWC + (size_t)h*WC + c;
  float*       orow = out + (size_t)b*HWC + (size_t)h*WC + c;

  float ring2[2]   = {0,0};
  float ring4[4]   = {0,0,0,0};
  float ring8[8]   = {0,0,0,0,0,0,0,0};
  float ring16[16] = {0,0,0,0,0,0,0,0,0,0,0,0,0,0,0,0};
  float T0 = 0.f, T1 = 0.f, T2 = 0.f, T3 = 0.f;
  float abuf[8] = {0,0,0,0,0,0,0,0};

  for (int t0 = 0; t0 < 48; t0 += 16) {
    #pragma unroll
    for (int u = 0; u < 16; ++u) {
      int t  = t0 + u;
      int wr = w0 - 7 + t;
      float m0 = 0.f, m1 = 0.f, m2 = 0.f, m3 = 0.f;
      if (wr >= 0 && wr < W) {
        int off = wr * C;
        m0 = pt[0][off] - fb[0]*pb[0][off];
        m1 = pt[1][off] - fb[1]*pb[1][off];
        m2 = pt[2][off] - fb[2]*pb[2][off];
        m3 = pt[3][off] - fb[3]*pb[3][off];
      }
      T0 += m0 - ring2[u&1];  ring2[u&1]  = m0;
      T1 += m1 - ring4[u&3];  ring4[u&3]  = m1;
      T2 += m2 - ring8[u&7];  ring8[u&7]  = m2;
      T3 += m3 - ring16[u];   ring16[u]   = m3;
      abuf[(u+7)&7] += c0 * __logf(fmaxf(T0, 0.f) + 1e-6f);
      abuf[(u+6)&7] += c1 * __logf(fmaxf(T1, 0.f) + 1e-6f);
      abuf[(u+4)&7] += c2 * __logf(fmaxf(T2, 0.f) + 1e-6f);
      abuf[u&7]     += c3 * __logf(fmaxf(T3, 0.f) + 1e-6f);
      int ig = w0 - 15 + t;
      if (t >= 15 && ig <= w0 + 27) {
        float alpha = abuf[u&7];
        float a = alpha * scl + bofs;
        float sc = 0.f;
        #pragma unroll
        for (int k = 0; k < K; ++k)
          sc += fmaxf(0.f, 1.f - wd[k]*fabsf(a - anc[k]));
        float sig = 1.f / (1.f + __expf(-sc));
        float xv = __builtin_nontemporal_load(&xrow[ig*C]);
        __builtin_nontemporal_store(xv + sig, &orow[ig*C]);
      }
      abuf[u&7] = 0.f;
    }
  }
}

// ================================ host ================================

extern "C" void kernel_launch(void* const* d_in, const int* in_sizes, int n_in,
                              void* d_out, int out_size, void* d_ws, size_t ws_size,
                              hipStream_t stream) {
  const float* x        = (const float*)d_in[0];
  const float* ols      = (const float*)d_in[1];
  const float* anchors  = (const float*)d_in[2];
  const float* hwidths  = (const float*)d_in[3];
  const float* bn_gamma = (const float*)d_in[4];
  const float* bn_beta  = (const float*)d_in[5];
  const float* bn_mean  = (const float*)d_in[6];
  const float* bn_var   = (const float*)d_in[7];
  float* out = (float*)d_out;

  if (ws_size >= 16384) {
    // fast path: min/max partials in ws, then the 2-chunk-ILP fused kernel.
    float* scratch = (float*)d_ws;   // [0..2047] mins, [2048..4095] maxs
    hipLaunchKernelGGL(k_minmax_part, dim3(2048), dim3(256), 0, stream, x, scratch);
    hipLaunchKernelGGL(k_fused2,      dim3(B*H),  dim3(128), 0, stream,
                       x, scratch, ols, anchors, hwidths,
                       bn_gamma, bn_beta, bn_mean, bn_var, out);
  } else {
    // fallback: verbatim R3 3-kernel pipeline (scratch in d_out, P in ws)
    float* P = (float*)d_ws;
    float* scratch = out;
    hipLaunchKernelGGL(k_minmax_part, dim3(2048),  dim3(256), 0, stream, x, scratch);
    hipLaunchKernelGGL(k_vpfx4,       dim3(B*W),   dim3(256), 0, stream, x, scratch, P);
    hipLaunchKernelGGL(k_main,        dim3(B*H*4), dim3(128), 0, stream,
                       P, x, ols, anchors, hwidths,
                       bn_gamma, bn_beta, bn_mean, bn_var, out);
  }
}

// Round 11
// 181.742 us; speedup vs baseline: 1.2398x; 1.0481x over previous
//
#include <hip/hip_runtime.h>
#include <math.h>

#define B 4
#define H 224
#define W 224
#define C 64
#define K 8
#define WC (W*C)        // 14336
#define HWC (H*W*C)     // 3211264

__device__ inline float wave_reduce_min(float v) {
  #pragma unroll
  for (int off = 32; off > 0; off >>= 1)
    v = fminf(v, __shfl_down(v, off, 64));
  return v;
}
__device__ inline float wave_reduce_max(float v) {
  #pragma unroll
  for (int off = 32; off > 0; off >>= 1)
    v = fmaxf(v, __shfl_down(v, off, 64));
  return v;
}

struct FalseT { static constexpr bool value = false; };
struct TrueT  { static constexpr bool value = true; };

// ================= FAST PATH =================

// ---- Kernel 0: per-block partial min/max per sample (verified R0/R3 body) ----
// Also pre-warms x into L3 for the fused kernel (R9: FETCH 52->36 MB).
__global__ __launch_bounds__(256) void k_minmax_part(const float* __restrict__ x,
                                                     float* __restrict__ scratch) {
  int s   = blockIdx.x >> 9;      // 512 blocks per sample
  int blk = blockIdx.x & 511;
  const float4* xs = (const float4*)(x + (size_t)s * HWC);
  const int n4 = HWC / 4;
  float vmin = INFINITY, vmax = -INFINITY;
  for (int i = blk*256 + threadIdx.x; i < n4; i += 512*256) {
    float4 v = xs[i];
    vmin = fminf(vmin, fminf(fminf(v.x, v.y), fminf(v.z, v.w)));
    vmax = fmaxf(vmax, fmaxf(fmaxf(v.x, v.y), fmaxf(v.z, v.w)));
  }
  __shared__ float smin[4], smax[4];
  float wmin = wave_reduce_min(vmin), wmax = wave_reduce_max(vmax);
  int wave = threadIdx.x >> 6, lane = threadIdx.x & 63;
  if (lane == 0) { smin[wave] = wmin; smax[wave] = wmax; }
  __syncthreads();
  if (threadIdx.x == 0) {
    float m = fminf(fminf(smin[0], smin[1]), fminf(smin[2], smin[3]));
    float M = fmaxf(fmaxf(smax[0], smax[1]), fmaxf(smax[2], smax[3]));
    scratch[blockIdx.x]        = m;
    scratch[2048 + blockIdx.x] = M;
  }
}

// ---- Kernel 1: FUSED, 28-wide chunks for occupancy (R11) -------------------
// R9's single-chunk wave body (VGPR ~84) on a finer decomposition:
// 8 chunks of 28 per row -> 7168 waves (vs R10's 1792; VGPR caps at
// 4 waves/SIMD = 4096 slots, so R10 ran the machine 40% empty).
// Block = 256 thr = 4 waves; wave handles chunk half*4+wave; 43 steps
// (15 warmup + 28 outputs, zero tail). Per-output math/order == R9.
__global__ __launch_bounds__(256) void k_fused28(
    const float* __restrict__ x, const float* __restrict__ scratch,
    const float* __restrict__ ols, const float* __restrict__ anchors,
    const float* __restrict__ hwidths, const float* __restrict__ bn_gamma,
    const float* __restrict__ bn_beta, const float* __restrict__ bn_mean,
    const float* __restrict__ bn_var, float* __restrict__ out) {
  int xcd  = blockIdx.x & 7;
  int i    = blockIdx.x >> 3;        // [0,224)
  int rg   = xcd * 112 + (i >> 1);   // global row in [0,896)
  int half = i & 1;
  int wave = threadIdx.x >> 6, c = threadIdx.x & 63;
  int b = rg / H, h = rg % H;
  int chunk = half * 4 + wave;       // [0,8)
  int w0 = chunk * 28;

  // --- finalize per-sample min/max from 512 partials (L2-hot, 2/thread) ---
  float vmn = fminf(scratch[b*512 + threadIdx.x], scratch[b*512 + 256 + threadIdx.x]);
  float vmx = fmaxf(scratch[2048 + b*512 + threadIdx.x],
                    scratch[2048 + b*512 + 256 + threadIdx.x]);
  vmn = wave_reduce_min(vmn);
  vmx = wave_reduce_max(vmx);
  __shared__ float smin[4], smax[4];
  if ((threadIdx.x & 63) == 0) { smin[wave] = vmn; smax[wave] = vmx; }
  __syncthreads();
  float xmin = fminf(fminf(smin[0], smin[1]), fminf(smin[2], smin[3]));
  float xmax = fmaxf(fmaxf(smax[0], smax[1]), fmaxf(smax[2], smax[3]));
  float rng  = xmax - xmin + 1e-6f;
  float epsp = 1e-6f * rng;          // eps lifted to the unnormalized domain

  const float LN2 = 0.69314718055994530942f;
  float wg0 = ols[0], wg1 = ols[1], wg2 = ols[2], wg3 = ols[3];
  float l0 = LN2, l1 = 2.f*LN2, l2 = 3.f*LN2, l3 = 4.f*LN2;
  float wsum = wg0 + wg1 + wg2 + wg3;
  float lrbar = (wg0*l0 + wg1*l1 + wg2*l2 + wg3*l3) / wsum;
  float d0 = l0-lrbar, d1 = l1-lrbar, d2 = l2-lrbar, d3 = l3-lrbar;
  float den = wg0*d0*d0 + wg1*d1*d1 + wg2*d2*d2 + wg3*d3*d3;
  float c0 = wg0*d0/den, c1 = wg1*d1/den, c2 = wg2*d2/den, c3 = wg3*d3/den;

  float scl  = bn_gamma[c] * rsqrtf(bn_var[c] + 1e-3f);
  float bofs = bn_beta[c] - bn_mean[c] * scl;
  float anc[K], wd[K];
  #pragma unroll
  for (int k = 0; k < K; ++k) { anc[k] = anchors[c*K + k]; wd[k] = hwidths[c*K + k]; }

  const int hiA[4] = {1, 2, 4, 8};
  const int loA[4] = {0, 1, 3, 7};
  const int rA[4]  = {2, 4, 8, 16};
  float Anh[4], Kin[4];
  #pragma unroll
  for (int s = 0; s < 4; ++s) {
    int ht = h + hiA[s]; if (ht > H-1) ht = H-1;
    int h0 = h - loA[s]; if (h0 < 0) h0 = 0;
    int nv = ht - h0 + 1;              // in-bounds rows of the vertical window
    Anh[s] = -(float)nv * xmin;        // per-column xmin correction factor
    Kin[s] = (float)rA[s] * Anh[s] + epsp;   // interior: nh == r, eps folded
  }

  // --- 16 row bases (block-uniform -> SGPRs; c folded into the lane offset) ---
  const float* rb[16]; float fr[16];
  const size_t sbase = (size_t)b * HWC;
  #pragma unroll
  for (int r16 = 0; r16 < 16; ++r16) {
    int r  = h - 7 + r16;
    int rc = r < 0 ? 0 : (r > H-1 ? H-1 : r);
    rb[r16] = x + sbase + (size_t)rc * WC;
    fr[r16] = (r >= 0 && r <= H-1) ? 1.f : 0.f;
  }

  float* orow = out + sbase + (size_t)h*WC + c;

  auto tloop = [&](auto EDGEC) {
    constexpr bool EDGE = decltype(EDGEC)::value;
    float ring2[2]   = {0,0};
    float ring4[4]   = {0,0,0,0};
    float ring8[8]   = {0,0,0,0,0,0,0,0};
    float ring16[16] = {0,0,0,0,0,0,0,0,0,0,0,0,0,0,0,0};
    float xring[8]   = {0,0,0,0,0,0,0,0};
    float T0 = 0.f, T1 = 0.f, T2 = 0.f, T3 = 0.f;
    float abuf[8] = {0,0,0,0,0,0,0,0};

    // One step; u must be compile-time (ring indices). Valid since every
    // sub-loop below starts at a t0 that is a multiple of 16.
    auto step = [&](int u, int t) {
      int wr = w0 - 7 + t;
      float m0, m1, m2, m3, xnew;
      if constexpr (EDGE) {
        m0 = m1 = m2 = m3 = 0.f; xnew = 0.f;
        if (wr >= 0 && wr < W) {
          int off = wr * C + c;
          float v00 = rb[0][off],  v01 = rb[1][off],  v02 = rb[2][off],  v03 = rb[3][off];
          float v04 = rb[4][off],  v05 = rb[5][off],  v06 = rb[6][off],  v07 = rb[7][off];
          float v08 = rb[8][off],  v09 = rb[9][off],  v10 = rb[10][off], v11 = rb[11][off];
          float v12 = rb[12][off], v13 = rb[13][off], v14 = rb[14][off], v15 = rb[15][off];
          m0 = fr[7]*v07 + fr[8]*v08;
          m1 = m0 + fr[6]*v06 + fr[9]*v09;
          m2 = m1 + fr[4]*v04 + fr[5]*v05 + fr[10]*v10 + fr[11]*v11;
          m3 = m2 + fr[0]*v00 + fr[1]*v01 + fr[2]*v02 + fr[3]*v03
                  + fr[12]*v12 + fr[13]*v13 + fr[14]*v14 + fr[15]*v15;
          xnew = v07;                      // row h always valid (fr[7]==1)
        }
      } else {
        int off = wr * C + c;
        float v00 = rb[0][off],  v01 = rb[1][off],  v02 = rb[2][off],  v03 = rb[3][off];
        float v04 = rb[4][off],  v05 = rb[5][off],  v06 = rb[6][off],  v07 = rb[7][off];
        float v08 = rb[8][off],  v09 = rb[9][off],  v10 = rb[10][off], v11 = rb[11][off];
        float v12 = rb[12][off], v13 = rb[13][off], v14 = rb[14][off], v15 = rb[15][off];
        m0 = fr[7]*v07 + fr[8]*v08;
        m1 = m0 + fr[6]*v06 + fr[9]*v09;
        m2 = m1 + fr[4]*v04 + fr[5]*v05 + fr[10]*v10 + fr[11]*v11;
        m3 = m2 + fr[0]*v00 + fr[1]*v01 + fr[2]*v02 + fr[3]*v03
                + fr[12]*v12 + fr[13]*v13 + fr[14]*v14 + fr[15]*v15;
        xnew = v07;
      }

      // x[h][ig] for the output 8 steps from now; read old slot BEFORE write.
      float xv_old = xring[u & 7];
      xring[u & 7] = xnew;

      T0 += m0 - ring2[u&1];    ring2[u&1]    = m0;
      T1 += m1 - ring4[u&3];    ring4[u&3]    = m1;
      T2 += m2 - ring8[u&7];    ring8[u&7]    = m2;
      T3 += m3 - ring16[u&15];  ring16[u&15]  = m3;

      float a0, a1, a2, a3;
      if constexpr (EDGE) {
        float nh0 = (float)(min(wr, W-1) - max(wr-1,  0) + 1);
        float nh1 = (float)(min(wr, W-1) - max(wr-3,  0) + 1);
        float nh2 = (float)(min(wr, W-1) - max(wr-7,  0) + 1);
        float nh3 = (float)(min(wr, W-1) - max(wr-15, 0) + 1);
        a0 = fmaxf(fmaf(Anh[0], nh0, T0) + epsp, epsp);
        a1 = fmaxf(fmaf(Anh[1], nh1, T1) + epsp, epsp);
        a2 = fmaxf(fmaf(Anh[2], nh2, T2) + epsp, epsp);
        a3 = fmaxf(fmaf(Anh[3], nh3, T3) + epsp, epsp);
      } else {
        a0 = fmaxf(T0 + Kin[0], epsp);
        a1 = fmaxf(T1 + Kin[1], epsp);
        a2 = fmaxf(T2 + Kin[2], epsp);
        a3 = fmaxf(T3 + Kin[3], epsp);
      }
      abuf[(u+7)&7] += c0 * __logf(a0);
      abuf[(u+6)&7] += c1 * __logf(a1);
      abuf[(u+4)&7] += c2 * __logf(a2);
      abuf[u&7]     += c3 * __logf(a3);

      if (t >= 15) {                       // ig in [w0, w0+27], no tail
        int ig = w0 - 15 + t;
        float a = abuf[u&7] * scl + bofs;
        float sc = 0.f;
        #pragma unroll
        for (int k = 0; k < K; ++k)
          sc += fmaxf(0.f, 1.f - wd[k]*fabsf(a - anc[k]));
        float sig = 1.f / (1.f + __expf(-sc));
        __builtin_nontemporal_store(xv_old + sig, &orow[ig*C]);
      }
      abuf[u&7] = 0.f;
    };

    // 43 steps total: 2 x 16 + 11-step epilogue (t0 = 32 is a multiple of 16).
    for (int t0 = 0; t0 < 32; t0 += 16) {
      #pragma unroll
      for (int u = 0; u < 16; ++u) step(u, t0 + u);
    }
    #pragma unroll
    for (int u = 0; u < 11; ++u) step(u, 32 + u);
  };
  // interior iff all loads in-bounds AND all 16-wide windows unclamped:
  // wr in [w0-7, w0+35]: w0 >= 22 (window start >= 0) && w0 <= 188 (wr <= 223)
  if (w0 >= 22 && w0 <= 188) tloop(FalseT{}); else tloop(TrueT{});
}

// ================= FALLBACK PATH (verbatim R3 pipeline) =================

__global__ __launch_bounds__(256) void k_vpfx4(const float* __restrict__ x,
                                               const float* __restrict__ scratch,
                                               float* __restrict__ P) {
  int bid = blockIdx.x;
  int b = bid / W, w = bid % W;
  int seg = threadIdx.x >> 4;
  int chg = threadIdx.x & 15;
  int wv  = threadIdx.x >> 6;

  float vmn = fminf(scratch[b*512 + threadIdx.x], scratch[b*512 + 256 + threadIdx.x]);
  float vmx = fmaxf(scratch[2048 + b*512 + threadIdx.x], scratch[2048 + b*512 + 256 + threadIdx.x]);
  __shared__ float smin[4], smax[4];
  float wmn = wave_reduce_min(vmn), wmx = wave_reduce_max(vmx);
  if ((threadIdx.x & 63) == 0) { smin[wv] = wmn; smax[wv] = wmx; }
  __syncthreads();
  float xmin = fminf(fminf(smin[0], smin[1]), fminf(smin[2], smin[3]));
  float xmax = fmaxf(fmaxf(smax[0], smax[1]), fmaxf(smax[2], smax[3]));
  float inv  = 1.0f / (xmax - xmin + 1e-6f);

  const size_t colbase = (size_t)b*HWC + (size_t)w*C;
  const float4* xp4 = (const float4*)(x + colbase);
  const int RS4 = WC / 4;
  const int r0 = seg * 14;

  float4 v4[14];
  #pragma unroll
  for (int j = 0; j < 14; ++j) v4[j] = xp4[(size_t)(r0 + j) * RS4 + chg];

  float4 s4 = v4[0];
  #pragma unroll
  for (int j = 1; j < 14; ++j) {
    s4.x += v4[j].x; s4.y += v4[j].y; s4.z += v4[j].z; s4.w += v4[j].w;
  }

  __shared__ float4 segsum[16][16];
  segsum[seg][chg] = s4;
  __syncthreads();

  float4 o4 = {0.f, 0.f, 0.f, 0.f};
  #pragma unroll
  for (int ss = 0; ss < 16; ++ss) {
    if (ss < seg) {
      float4 t = segsum[ss][chg];
      o4.x += t.x; o4.y += t.y; o4.z += t.z; o4.w += t.w;
    }
  }

  float4* Pp4 = (float4*)(P + colbase);
  float ax = o4.x, ay = o4.y, az = o4.z, aw = o4.w;
  #pragma unroll
  for (int j = 0; j < 14; ++j) {
    ax += v4[j].x; ay += v4[j].y; az += v4[j].z; aw += v4[j].w;
    float sub = (float)(r0 + j + 1) * xmin;
    float4 outv;
    outv.x = (ax - sub) * inv;
    outv.y = (ay - sub) * inv;
    outv.z = (az - sub) * inv;
    outv.w = (aw - sub) * inv;
    Pp4[(size_t)(r0 + j) * RS4 + chg] = outv;
  }
}

__global__ __launch_bounds__(128) void k_main(
    const float* __restrict__ P, const float* __restrict__ x,
    const float* __restrict__ ols, const float* __restrict__ anchors,
    const float* __restrict__ hwidths, const float* __restrict__ bn_gamma,
    const float* __restrict__ bn_beta, const float* __restrict__ bn_mean,
    const float* __restrict__ bn_var, float* __restrict__ out) {
  int xcd  = blockIdx.x & 7;
  int i    = blockIdx.x >> 3;
  int rg   = xcd * 112 + (i >> 2);
  int wave = threadIdx.x >> 6, c = threadIdx.x & 63;
  int chunk = (i & 3) * 2 + wave;
  int b = rg / H, h = rg % H;
  int w0 = chunk * 28;

  const float LN2 = 0.69314718055994530942f;
  float wg0 = ols[0], wg1 = ols[1], wg2 = ols[2], wg3 = ols[3];
  float l0 = LN2, l1 = 2.f*LN2, l2 = 3.f*LN2, l3 = 4.f*LN2;
  float wsum = wg0 + wg1 + wg2 + wg3;
  float lrbar = (wg0*l0 + wg1*l1 + wg2*l2 + wg3*l3) / wsum;
  float d0 = l0-lrbar, d1 = l1-lrbar, d2 = l2-lrbar, d3 = l3-lrbar;
  float den = wg0*d0*d0 + wg1*d1*d1 + wg2*d2*d2 + wg3*d3*d3;
  float c0 = wg0*d0/den, c1 = wg1*d1/den, c2 = wg2*d2/den, c3 = wg3*d3/den;

  float scl  = bn_gamma[c] * rsqrtf(bn_var[c] + 1e-3f);
  float bofs = bn_beta[c] - bn_mean[c] * scl;
  float anc[K], wd[K];
  #pragma unroll
  for (int k = 0; k < K; ++k) { anc[k] = anchors[c*K + k]; wd[k] = hwidths[c*K + k]; }

  const int hiA[4] = {1, 2, 4, 8};
  const int loA[4] = {0, 1, 3, 7};
  const float* pt[4]; const float* pb[4]; float fb[4];
  #pragma unroll
  for (int s = 0; s < 4; ++s) {
    int ht = h + hiA[s]; if (ht > H-1) ht = H-1;
    int hb = h - loA[s] - 1;
    int hbc = hb < 0 ? 0 : hb;
    pt[s] = P + (size_t)b*HWC + (size_t)ht*WC + c;
    pb[s] = P + (size_t)b*HWC + (size_t)hbc*WC + c;
    fb[s] = hb < 0 ? 0.f : 1.f;
  }

  const float* xrow = x   + (size_t)b*HWC + (size_t)h*WC + c;
  float*       orow = out + (size_t)b*HWC + (size_t)h*WC + c;

  float ring2[2]   = {0,0};
  float ring4[4]   = {0,0,0,0};
  float ring8[8]   = {0,0,0,0,0,0,0,0};
  float ring16[16] = {0,0,0,0,0,0,0,0,0,0,0,0,0,0,0,0};
  float T0 = 0.f, T1 = 0.f, T2 = 0.f, T3 = 0.f;
  float abuf[8] = {0,0,0,0,0,0,0,0};

  for (int t0 = 0; t0 < 48; t0 += 16) {
    #pragma unroll
    for (int u = 0; u < 16; ++u) {
      int t  = t0 + u;
      int wr = w0 - 7 + t;
      float m0 = 0.f, m1 = 0.f, m2 = 0.f, m3 = 0.f;
      if (wr >= 0 && wr < W) {
        int off = wr * C;
        m0 = pt[0][off] - fb[0]*pb[0][off];
        m1 = pt[1][off] - fb[1]*pb[1][off];
        m2 = pt[2][off] - fb[2]*pb[2][off];
        m3 = pt[3][off] - fb[3]*pb[3][off];
      }
      T0 += m0 - ring2[u&1];  ring2[u&1]  = m0;
      T1 += m1 - ring4[u&3];  ring4[u&3]  = m1;
      T2 += m2 - ring8[u&7];  ring8[u&7]  = m2;
      T3 += m3 - ring16[u];   ring16[u]   = m3;
      abuf[(u+7)&7] += c0 * __logf(fmaxf(T0, 0.f) + 1e-6f);
      abuf[(u+6)&7] += c1 * __logf(fmaxf(T1, 0.f) + 1e-6f);
      abuf[(u+4)&7] += c2 * __logf(fmaxf(T2, 0.f) + 1e-6f);
      abuf[u&7]     += c3 * __logf(fmaxf(T3, 0.f) + 1e-6f);
      int ig = w0 - 15 + t;
      if (t >= 15 && ig <= w0 + 27) {
        float alpha = abuf[u&7];
        float a = alpha * scl + bofs;
        float sc = 0.f;
        #pragma unroll
        for (int k = 0; k < K; ++k)
          sc += fmaxf(0.f, 1.f - wd[k]*fabsf(a - anc[k]));
        float sig = 1.f / (1.f + __expf(-sc));
        float xv = __builtin_nontemporal_load(&xrow[ig*C]);
        __builtin_nontemporal_store(xv + sig, &orow[ig*C]);
      }
      abuf[u&7] = 0.f;
    }
  }
}

// ================================ host ================================

extern "C" void kernel_launch(void* const* d_in, const int* in_sizes, int n_in,
                              void* d_out, int out_size, void* d_ws, size_t ws_size,
                              hipStream_t stream) {
  const float* x        = (const float*)d_in[0];
  const float* ols      = (const float*)d_in[1];
  const float* anchors  = (const float*)d_in[2];
  const float* hwidths  = (const float*)d_in[3];
  const float* bn_gamma = (const float*)d_in[4];
  const float* bn_beta  = (const float*)d_in[5];
  const float* bn_mean  = (const float*)d_in[6];
  const float* bn_var   = (const float*)d_in[7];
  float* out = (float*)d_out;

  if (ws_size >= 16384) {
    // fast path: min/max partials in ws, then 28-wide fused kernel (7168 waves)
    float* scratch = (float*)d_ws;   // [0..2047] mins, [2048..4095] maxs
    hipLaunchKernelGGL(k_minmax_part, dim3(2048),  dim3(256), 0, stream, x, scratch);
    hipLaunchKernelGGL(k_fused28,     dim3(B*H*2), dim3(256), 0, stream,
                       x, scratch, ols, anchors, hwidths,
                       bn_gamma, bn_beta, bn_mean, bn_var, out);
  } else {
    // fallback: verbatim R3 3-kernel pipeline (scratch in d_out, P in ws)
    float* P = (float*)d_ws;
    float* scratch = out;
    hipLaunchKernelGGL(k_minmax_part, dim3(2048),  dim3(256), 0, stream, x, scratch);
    hipLaunchKernelGGL(k_vpfx4,       dim3(B*W),   dim3(256), 0, stream, x, scratch, P);
    hipLaunchKernelGGL(k_main,        dim3(B*H*4), dim3(128), 0, stream,
                       P, x, ols, anchors, hwidths,
                       bn_gamma, bn_beta, bn_mean, bn_var, out);
  }
}